// Round 7
// baseline (135.551 us; speedup 1.0000x reference)
//
#include <hip/hip_runtime.h>
#include <stdint.h>

// RPN RoI proposal, 5-kernel pipeline (each phase isolated for rocprof +
// data-parallel phases spread across all CUs):
//  K1 (B*8 x 256): score pass -> per-slice histogram (global atomic flush)
//     + speculative gather of keys with bin>=CONS into g_pairs (superset of
//     top-2000, E=2812, cap 4096). key = flip(f32)<<32 | bin<<20 |
//     (0xFFFFF-idx): u64 desc sort == lax.top_k order (incl. tie-break).
//  K2 (B x 1024): hist suffix-scan -> bsel/tprime; filter superset (or exact
//     re-gather fallback); exact pivot among bin==bsel candidates; register
//     bitonic sort of 2048 u64 -> g_sorted.
//  K3 (B*4 x 256): decode 512 ranks/block -> g_boxes, g_area.
//  K4 (B*4 x 256): 128 supmat rows/block x 16 words (boxes staged in LDS,
//     lanes vary row -> wave-broadcast column reads) -> g_supmat[512][16].
//  K5 (B x 64): stage supmat into padded LDS [512][18]; chunked greedy
//     sweep (64-wide chunks, wave-uniform scalar resolve via readlane, kept
//     rows OR'd into 16-lane removed mask); early-exit at 300 kept;
//     slow-but-correct fallback beyond row 512 (never taken); write
//     clipped [300,4] zero-padded.

#define PRE 2000
#define POST 300
#define TILE 512
#define IOU_THR 0.7f
#define EPSV 1e-8f
#define SORTN 2048
#define NBINS 2048
#define CANDCAP 512
#define PCAP 4096
#define CONS 1984
#define SL 8
#define KBUF 1536
#define SSTR 18          // padded supmat row stride (words) in K5 LDS

typedef unsigned long long u64;

__device__ __forceinline__ uint32_t flip_f32(uint32_t b) {
    return b ^ ((uint32_t)((int32_t)b >> 31) | 0x80000000u);
}

__device__ __forceinline__ int bin_of(float s) {
    int bn = (int)(s * 2048.0f);
    return min(max(bn, 0), NBINS - 1);
}

__device__ __forceinline__ u64 make_key(float s, int idx, int bn) {
    uint32_t ub = flip_f32(__float_as_uint(s));
    return ((u64)ub << 32) | ((uint32_t)bn << 20) |
           (uint32_t)(0xFFFFF - idx);
}

__device__ __forceinline__ bool iou_gt(const float4& bi, float ai,
                                       const float4& bj, float aj) {
    float yy1 = fmaxf(bi.x, bj.x);
    float xx1 = fmaxf(bi.y, bj.y);
    float yy2 = fminf(bi.z, bj.z);
    float xx2 = fminf(bi.w, bj.w);
    float inter = fmaxf(yy2 - yy1, 0.f) * fmaxf(xx2 - xx1, 0.f);
    float iou = inter / (ai + aj - inter + EPSV);
    return iou > IOU_THR;
}

__device__ __forceinline__ u64 cs_keep(u64 v, u64 pv, int i, int j, int k) {
    bool lower   = ((i & j) == 0);
    bool desc    = ((i & k) == 0);
    bool keepmax = (desc == lower);
    u64 mx = v > pv ? v : pv;
    u64 mn = v > pv ? pv : v;
    return keepmax ? mx : mn;
}

__device__ __forceinline__ int wave_append(bool pred, int lane, int* cnt) {
    u64 bal = __ballot(pred);
    if (!bal) return -1;
    int tot = __popcll(bal);
    int fl  = __ffsll(bal) - 1;
    int base = 0;
    if (lane == fl) base = atomicAdd(cnt, tot);
    base = __shfl(base, fl, 64);
    return base + __popcll(bal & ((1ull << lane) - 1));
}

// ---------------- K1: histogram + speculative gather -----------------------
__global__ __launch_bounds__(256) void k1_hist_gather(
    const float4* __restrict__ score4,
    uint32_t* __restrict__ g_hist,
    u64*      __restrict__ g_pairs,
    int*      __restrict__ g_cnt,
    int*      __restrict__ g_ovf,
    int N)
{
    const int blk = blockIdx.x;
    const int b   = blk / SL;
    const int s   = blk % SL;
    const int tid = threadIdx.x;
    const int F4PB = N >> 2;
    const int F4PS = (F4PB + SL - 1) / SL;

    __shared__ uint32_t hist[NBINS];
    __shared__ u64 keybuf[KBUF];
    __shared__ int kcnt, kbase;

    for (int i = tid; i < NBINS; i += 256) hist[i] = 0u;
    if (tid == 0) kcnt = 0;
    __syncthreads();

    const float4* src = score4 + (size_t)b * F4PB;
    const int n0 = s * F4PS, n1 = min(n0 + F4PS, F4PB);
    for (int n = n0 + tid; n < n1; n += 256) {
        float4 v = src[n];
        float sv[4] = {v.x, v.y, v.z, v.w};
#pragma unroll
        for (int c = 0; c < 4; ++c) {
            int bn = bin_of(sv[c]);
            atomicAdd(&hist[bn], 1u);
            if (bn >= CONS) {
                int q = atomicAdd(&kcnt, 1);
                if (q < KBUF) keybuf[q] = make_key(sv[c], 4 * n + c, bn);
            }
        }
    }
    __syncthreads();

    uint32_t* gh = g_hist + (size_t)b * NBINS;
    for (int i = tid; i < NBINS; i += 256) {
        uint32_t h = hist[i];
        if (h) atomicAdd(&gh[i], h);
    }
    int lc = min(kcnt, KBUF);
    if (tid == 0) {
        if (kcnt > KBUF) atomicOr(&g_ovf[b], 1);
        kbase = atomicAdd(&g_cnt[b], lc);
    }
    __syncthreads();
    int base = kbase;
    if (base + lc > PCAP) {
        if (tid == 0) atomicOr(&g_ovf[b], 1);
        lc = max(0, PCAP - base);
    }
    u64* gp = g_pairs + (size_t)b * PCAP + base;
    for (int i = tid; i < lc; i += 256) gp[i] = keybuf[i];
}

// ---------------- K2: select + filter + pivot + sort -----------------------
__global__ __launch_bounds__(1024) void k2_sort(
    const float4* __restrict__ score4,
    const u64*  __restrict__ g_pairs,
    const int*  __restrict__ g_cnt,
    const int*  __restrict__ g_ovf,
    const uint32_t* __restrict__ g_hist,
    u64* __restrict__ g_sorted,
    int N)
{
    const int b    = blockIdx.x;
    const int tid  = threadIdx.x;
    const int lane = tid & 63;
    const int wv   = tid >> 6;

    __shared__ u64 pairs[SORTN];
    __shared__ u64 cand[CANDCAP];
    __shared__ uint32_t wtot[16];
    __shared__ int sh_bsel, sh_tprime, sh_cnt, sh_nc;
    __shared__ uint32_t sh_pivot;

    const int F4PB = N >> 2;

    // hist staged in pairs region
    uint32_t* hist = (uint32_t*)pairs;
    hist[tid]        = g_hist[(size_t)b * NBINS + tid];
    hist[tid + 1024] = g_hist[(size_t)b * NBINS + tid + 1024];
    if (tid == 0) { sh_cnt = 0; sh_nc = 0; }
    __syncthreads();
    {
        const int i0 = wv * 128 + lane;
        const int i1 = i0 + 64;
        int h0 = (int)hist[i0];
        int h1 = (int)hist[i1];
        int s0 = h0, s1 = h1;
#pragma unroll
        for (int off = 1; off < 64; off <<= 1) {
            int t0 = __shfl_down(s0, off, 64);
            int t1 = __shfl_down(s1, off, 64);
            if (lane + off < 64) { s0 += t0; s1 += t1; }
        }
        int sum_h1 = __shfl(s1, 0, 64);
        if (lane == 0) wtot[wv] = (uint32_t)(__shfl(s0, 0, 64) + sum_h1);
        __syncthreads();
        int offtot = 0;
        for (int w2 = wv + 1; w2 < 16; ++w2) offtot += (int)wtot[w2];
        int S0 = s0 + sum_h1 + offtot;
        int S1 = s1 + offtot;
        if (S0 >= PRE && S0 - h0 < PRE) { sh_bsel = i0; sh_tprime = PRE - (S0 - h0); }
        if (S1 >= PRE && S1 - h1 < PRE) { sh_bsel = i1; sh_tprime = PRE - (S1 - h1); }
    }
    __syncthreads();
    const int bsel   = sh_bsel;
    const int tprime = sh_tprime;
    const bool flag  = (bsel < CONS) || (g_cnt[b] > PCAP) || g_ovf[b];
    __syncthreads();        // hist consumed; pairs writable

    if (!flag) {
        const int  nk = min(g_cnt[b], PCAP);
        const u64* gp = g_pairs + (size_t)b * PCAP;
        for (int i0 = 0; i0 < nk; i0 += 1024) {
            int i = i0 + tid;
            bool valid = (i < nk);
            u64 key = valid ? gp[i] : 0ull;
            int bn = (int)((key >> 20) & 0xFFFu);
            bool isP = valid && (bn > bsel);
            bool isC = valid && (bn == bsel);
            int sp = wave_append(isP, lane, &sh_cnt);
            if (isP && sp < SORTN) pairs[sp] = key;
            int sc = wave_append(isC, lane, &sh_nc);
            if (isC && sc < CANDCAP) cand[sc] = key;
        }
    } else {
        const float4* src = score4 + (size_t)b * F4PB;
        for (int n = tid; n < F4PB; n += 1024) {
            float4 v = src[n];
            float sv[4] = {v.x, v.y, v.z, v.w};
#pragma unroll
            for (int c = 0; c < 4; ++c) {
                int bn = bin_of(sv[c]);
                if (bn >= bsel) {
                    u64 key = make_key(sv[c], 4 * n + c, bn);
                    if (bn > bsel) {
                        int q = atomicAdd(&sh_cnt, 1);
                        if (q < SORTN) pairs[q] = key;
                    } else {
                        int t = atomicAdd(&sh_nc, 1);
                        if (t < CANDCAP) cand[t] = key;
                    }
                }
            }
        }
    }
    __syncthreads();

    // exact pivot among candidates (rank tprime on exact f32 bits)
    const int nc = min(sh_nc, CANDCAP);
    for (int i = tid; i < nc; i += 1024) {
        uint32_t vi = (uint32_t)(cand[i] >> 32);
        int g = 0, e = 0;
        for (int j = 0; j < nc; ++j) {
            uint32_t vj = (uint32_t)(cand[j] >> 32);
            g += (vj > vi);
            e += (vj == vi);
        }
        if (g < tprime && g + e >= tprime) sh_pivot = vi;
    }
    __syncthreads();
    const uint32_t pivot = sh_pivot;
    for (int i = tid; i < nc; i += 1024) {
        uint32_t vi = (uint32_t)(cand[i] >> 32);
        if (vi >= pivot) {
            int q = atomicAdd(&sh_cnt, 1);
            if (q < SORTN) pairs[q] = cand[i];
        }
    }
    __syncthreads();
    const int total = min(sh_cnt, SORTN);
    for (int q = total + tid; q < SORTN; q += 1024)
        pairs[q] = 0ull;
    __syncthreads();

    // bitonic sort in registers (2 elems/lane x 16 waves)
    {
        const int i0 = wv * 128 + lane;
        const int i1 = i0 + 64;
        u64 e0 = pairs[i0];
        u64 e1 = pairs[i1];
        for (int k = 2; k <= SORTN; k <<= 1) {
            for (int j = k >> 1; j > 0; j >>= 1) {
                if (j >= 128) {
                    pairs[i0] = e0;
                    pairs[i1] = e1;
                    __syncthreads();
                    u64 p0 = pairs[i0 ^ j];
                    u64 p1 = pairs[i1 ^ j];
                    __syncthreads();
                    e0 = cs_keep(e0, p0, i0, j, k);
                    e1 = cs_keep(e1, p1, i1, j, k);
                } else if (j == 64) {
                    u64 a = e0, c = e1;
                    e0 = cs_keep(a, c, i0, 64, k);
                    e1 = cs_keep(c, a, i1, 64, k);
                } else {
                    e0 = cs_keep(e0, __shfl_xor(e0, j, 64), i0, j, k);
                    e1 = cs_keep(e1, __shfl_xor(e1, j, 64), i1, j, k);
                }
            }
        }
        g_sorted[(size_t)b * SORTN + i0] = e0;
        g_sorted[(size_t)b * SORTN + i1] = e1;
    }
}

// ---------------- K3: decode sorted top-2000 -------------------------------
__global__ __launch_bounds__(256) void k3_decode(
    const float4* __restrict__ deltas,
    const float4* __restrict__ anchors,
    const u64*  __restrict__ g_sorted,
    float4* __restrict__ g_boxes,
    float*  __restrict__ g_area,
    int N)
{
    const int b   = blockIdx.x >> 2;
    const int s   = blockIdx.x & 3;
    const int tid = threadIdx.x;
    const int r0 = s * 512, r1 = min(r0 + 512, PRE);

    const float4* dl = deltas + (size_t)b * N;
    for (int r = r0 + tid; r < r1; r += 256) {
        u64 key = g_sorted[(size_t)b * SORTN + r];
        uint32_t idx = 0xFFFFFu - (uint32_t)(key & 0xFFFFFull);
        float4 bx = make_float4(0.f, 0.f, 0.f, 0.f);
        float  ar = 0.f;
        if (idx < (uint32_t)N) {
            float4 d  = dl[idx];
            float4 an = anchors[idx];
            float ah  = an.z - an.x;
            float aw  = an.w - an.y;
            float acy = an.x + 0.5f * ah;
            float acx = an.y + 0.5f * aw;
            float h   = expf(d.z) * ah;
            float w   = expf(d.w) * aw;
            float cy  = d.x * ah + acy;
            float cx  = d.y * aw + acx;
            float y1  = cy - 0.5f * h;
            float x1  = cx - 0.5f * w;
            bx = make_float4(y1, x1, y1 + h, x1 + w);
            ar = fmaxf(bx.z - bx.x, 0.f) * fmaxf(bx.w - bx.y, 0.f);
        }
        g_boxes[(size_t)b * PRE + r] = bx;
        g_area [(size_t)b * PRE + r] = ar;
    }
}

// ---------------- K4: suppression matrix [512][16] -------------------------
__global__ __launch_bounds__(256) void k4_supmat(
    const float4* __restrict__ g_boxes,
    const float*  __restrict__ g_area,
    uint32_t* __restrict__ g_supmat)
{
    const int b   = blockIdx.x >> 2;
    const int s   = blockIdx.x & 3;
    const int tid = threadIdx.x;

    __shared__ float4 box[TILE];
    __shared__ float  area[TILE];
    for (int i = tid; i < TILE; i += 256) {
        box[i]  = g_boxes[(size_t)b * PRE + i];
        area[i] = g_area [(size_t)b * PRE + i];
    }
    __syncthreads();

    // rows [s*128, s*128+128) x 16 words; lanes vary row -> broadcast cols
    for (int idx = tid; idx < 128 * 16; idx += 256) {
        int rl  = idx & 127;
        int w   = idx >> 7;              // wave-uniform (128 >= 64)
        int row = s * 128 + rl;
        int jbase = w << 5;
        float4 bi = box[row];
        float  ai = area[row];
        uint32_t bits = 0u;
        if (jbase + 31 > row) {
#pragma unroll
            for (int c = 0; c < 32; ++c) {
                int j = jbase + c;
                if (j > row && iou_gt(bi, ai, box[j], area[j]))
                    bits |= (1u << c);
            }
        }
        g_supmat[((size_t)b * TILE + row) * 16 + w] = bits;
    }
}

// ---------------- K5: chunked greedy sweep + output ------------------------
__global__ __launch_bounds__(64) void k5_sweep(
    const uint32_t* __restrict__ g_supmat,
    const float4* __restrict__ g_boxes,
    const float*  __restrict__ g_area,
    float4* __restrict__ out)
{
    const int b    = blockIdx.x;
    const int lane = threadIdx.x;

    __shared__ uint32_t sup[TILE][SSTR];
    __shared__ uint32_t kept[POST];
    __shared__ u64 sh_keepbits[TILE / 64];
    __shared__ uint32_t fmask[(PRE - TILE + 31) / 32];
    __shared__ int sh_kc;

    // stage supmat into padded LDS (uint2 = 8B chunks, coalesced)
    {
        const uint2* gs = (const uint2*)(g_supmat + (size_t)b * TILE * 16);
        for (int idx = lane; idx < TILE * 8; idx += 64) {
            int row = idx >> 3, h = idx & 7;
            uint2 v = gs[idx];
            *(uint2*)&sup[row][2 * h] = v;
        }
    }
    __syncthreads();

    // chunked greedy sweep (wave-uniform scalar resolve)
    {
        uint32_t removedw = 0u;          // lanes 0..15: removed word
        int kc = 0, nq = 0;
        for (int q = 0; q < TILE / 64; ++q) {
            const int cbase = q << 6;
            u64 rowchunk = *(const u64*)(&sup[cbase + lane][2 * q]);
            uint32_t rcl = (uint32_t)rowchunk;
            uint32_t rch = (uint32_t)(rowchunk >> 32);
            uint32_t rlo = (uint32_t)__builtin_amdgcn_readlane((int)removedw, 2 * q);
            uint32_t rhi = (uint32_t)__builtin_amdgcn_readlane((int)removedw, 2 * q + 1);
            u64 avail = ~(((u64)rhi << 32) | rlo);
            u64 keep = 0ull;
            while (avail) {
                int i = __ffsll(avail) - 1;
                keep |= (1ull << i);
                u64 row_i =
                    ((u64)(uint32_t)__builtin_amdgcn_readlane((int)rch, i) << 32) |
                    (uint32_t)__builtin_amdgcn_readlane((int)rcl, i);
                avail &= ~((1ull << i) | row_i);
            }
            if (lane == 0) sh_keepbits[q] = keep;
            kc += __popcll(keep);
            nq = q + 1;
            if (kc >= POST) break;
            u64 kb = keep;
            while (kb) {
                int c0 = __ffsll(kb) - 1; kb &= kb - 1;
                int c1 = c0, c2 = c0, c3 = c0;
                if (kb) { c1 = __ffsll(kb) - 1; kb &= kb - 1; }
                if (kb) { c2 = __ffsll(kb) - 1; kb &= kb - 1; }
                if (kb) { c3 = __ffsll(kb) - 1; kb &= kb - 1; }
                if (lane < 16) {
                    uint32_t a0 = sup[cbase + c0][lane];
                    uint32_t a1 = sup[cbase + c1][lane];
                    uint32_t a2 = sup[cbase + c2][lane];
                    uint32_t a3 = sup[cbase + c3][lane];
                    removedw |= (a0 | a1 | a2 | a3);
                }
            }
        }
        int base = 0;
        for (int q = 0; q < nq; ++q) {
            u64 kbq = sh_keepbits[q];
            int pos = base + __popcll(kbq & ((1ull << lane) - 1));
            if (((kbq >> lane) & 1ull) && pos < POST)
                kept[pos] = (uint32_t)(q * 64 + lane);
            base += __popcll(kbq);
        }
        if (lane == 0) sh_kc = min(kc, POST);
    }
    __syncthreads();
    int kc = sh_kc;

    // fallback beyond row 512 (slow but exact; not taken on this data)
    if (kc < POST) {
        for (int w = lane; w < (PRE - TILE + 31) / 32; w += 64) fmask[w] = 0u;
        __syncthreads();
        for (int j = TILE + lane; j < PRE; j += 64) {
            float4 bj = g_boxes[(size_t)b * PRE + j];
            float  aj = g_area [(size_t)b * PRE + j];
            bool supd = false;
            for (int k = 0; k < kc; ++k) {
                int i = (int)kept[k];
                float4 bi = g_boxes[(size_t)b * PRE + i];
                float  ai = g_area [(size_t)b * PRE + i];
                if (iou_gt(bi, ai, bj, aj)) { supd = true; break; }
            }
            if (supd) atomicOr(&fmask[(j - TILE) >> 5], 1u << ((j - TILE) & 31));
        }
        __syncthreads();
        int i = TILE;
        while (i < PRE && kc < POST) {
            while (i < PRE && ((fmask[(i - TILE) >> 5] >> ((i - TILE) & 31)) & 1u)) ++i;
            if (i >= PRE) break;
            if (lane == 0) kept[kc] = (uint32_t)i;
            ++kc;
            if (kc >= POST) break;
            float4 bi = g_boxes[(size_t)b * PRE + i];
            float  ai = g_area [(size_t)b * PRE + i];
            for (int j = i + 1 + lane; j < PRE; j += 64) {
                float4 bj = g_boxes[(size_t)b * PRE + j];
                float  aj = g_area [(size_t)b * PRE + j];
                if (iou_gt(bi, ai, bj, aj))
                    atomicOr(&fmask[(j - TILE) >> 5], 1u << ((j - TILE) & 31));
            }
            ++i;
            __syncthreads();
        }
    }
    __syncthreads();

    // write clipped output
    float4* ob = out + (size_t)b * POST;
    for (int r = lane; r < POST; r += 64) {
        float4 o = make_float4(0.f, 0.f, 0.f, 0.f);
        if (r < kc) {
            float4 bx = g_boxes[(size_t)b * PRE + kept[r]];
            o.x = fminf(fmaxf(bx.x, 0.f), 1.f);
            o.y = fminf(fmaxf(bx.y, 0.f), 1.f);
            o.z = fminf(fmaxf(bx.z, 0.f), 1.f);
            o.w = fminf(fmaxf(bx.w, 0.f), 1.f);
        }
        ob[r] = o;
    }
}

extern "C" void kernel_launch(void* const* d_in, const int* in_sizes, int n_in,
                              void* d_out, int out_size, void* d_ws, size_t ws_size,
                              hipStream_t stream) {
    const float4* deltas  = (const float4*)d_in[0];
    const float*  labels  = (const float*)d_in[1];
    const float4* anchors = (const float4*)d_in[2];
    const float4* score4  = (const float4*)labels;
    float4*       outp    = (float4*)d_out;
    const int N = in_sizes[2] / 4;      // 90000
    const int B = in_sizes[1] / N;      // 64

    // workspace layout (16B-aligned chunks):
    // boxes | pairs | sorted | supmat | area | hist | cnt | ovf
    char* ws = (char*)d_ws;
    const size_t SZ_BOXES  = (size_t)B * PRE * 16;
    const size_t SZ_PAIRS  = (size_t)B * PCAP * 8;
    const size_t SZ_SORTED = (size_t)B * SORTN * 8;
    const size_t SZ_SUPMAT = (size_t)B * TILE * 16 * 4;
    const size_t SZ_AREA   = (size_t)B * PRE * 4;
    float4*   g_boxes  = (float4*)ws;
    u64*      g_pairs  = (u64*)(ws + SZ_BOXES);
    u64*      g_sorted = (u64*)(ws + SZ_BOXES + SZ_PAIRS);
    uint32_t* g_supmat = (uint32_t*)(ws + SZ_BOXES + SZ_PAIRS + SZ_SORTED);
    float*    g_area   = (float*)(ws + SZ_BOXES + SZ_PAIRS + SZ_SORTED + SZ_SUPMAT);
    uint32_t* g_hist   = (uint32_t*)(ws + SZ_BOXES + SZ_PAIRS + SZ_SORTED + SZ_SUPMAT + SZ_AREA);
    int*      g_cnt    = (int*)((char*)g_hist + (size_t)B * NBINS * 4);
    int*      g_ovf    = g_cnt + B;

    size_t zbytes = (size_t)B * NBINS * 4 + (size_t)B * 4 * 2;
    hipMemsetAsync((void*)g_hist, 0, zbytes, stream);

    k1_hist_gather<<<B * SL, 256, 0, stream>>>(score4, g_hist, g_pairs,
                                               g_cnt, g_ovf, N);
    k2_sort<<<B, 1024, 0, stream>>>(score4, g_pairs, g_cnt, g_ovf, g_hist,
                                    g_sorted, N);
    k3_decode<<<B * 4, 256, 0, stream>>>(deltas, anchors, g_sorted,
                                         g_boxes, g_area, N);
    k4_supmat<<<B * 4, 256, 0, stream>>>(g_boxes, g_area, g_supmat);
    k5_sweep<<<B, 64, 0, stream>>>(g_supmat, g_boxes, g_area, outp);
}

// Round 8
// 117.370 us; speedup vs baseline: 1.1549x; 1.1549x over previous
//
#include <hip/hip_runtime.h>
#include <stdint.h>

// RPN RoI proposal, 5-kernel pipeline, ZERO pre-zeroed state (no memset):
//  K1 (B*8 x 256): score pass -> per-slice histogram [B][SL][2048] written
//     with plain stores + speculative per-slice key gather (bin>=CONS) into
//     private segments g_pairs[(b,s)][KBUF], raw count in g_scnt (plain
//     store). key = flip(f32)<<32 | bin<<20 | (0xFFFFF-idx): u64 desc sort
//     == lax.top_k order (incl. ascending-index tie-break).
//  K2 (B x 1024): sum 8 slice hists during LDS load; suffix-scan -> bsel/
//     tprime; filter the 8 segments (or exact re-gather fallback if bsel <
//     CONS or any slice overflowed); exact pivot among bin==bsel candidates;
//     register bitonic sort of 2048 u64 -> g_sorted.
//  K3 (B*4 x 256): decode 512 ranks/block -> g_boxes, g_area.
//  K4 (B*4 x 256): 128 supmat rows/block x 16 words (boxes staged in LDS,
//     lanes vary row -> wave-broadcast column reads) -> g_supmat[512][16].
//  K5 (B x 256): stage supmat into padded LDS [512][18] (256 threads);
//     wave-0 chunked greedy sweep (64-wide chunks, wave-uniform scalar
//     resolve via readlane, kept rows OR'd into 16-lane removed mask);
//     early-exit at 300 kept; exact fallback beyond row 512 (never taken);
//     write clipped [300,4] zero-padded.

#define PRE 2000
#define POST 300
#define TILE 512
#define IOU_THR 0.7f
#define EPSV 1e-8f
#define SORTN 2048
#define NBINS 2048
#define CANDCAP 512
#define CONS 1984
#define SL 8
#define KBUF 1536
#define SSTR 18          // padded supmat row stride (words) in K5 LDS

typedef unsigned long long u64;

__device__ __forceinline__ uint32_t flip_f32(uint32_t b) {
    return b ^ ((uint32_t)((int32_t)b >> 31) | 0x80000000u);
}

__device__ __forceinline__ int bin_of(float s) {
    int bn = (int)(s * 2048.0f);
    return min(max(bn, 0), NBINS - 1);
}

__device__ __forceinline__ u64 make_key(float s, int idx, int bn) {
    uint32_t ub = flip_f32(__float_as_uint(s));
    return ((u64)ub << 32) | ((uint32_t)bn << 20) |
           (uint32_t)(0xFFFFF - idx);
}

__device__ __forceinline__ bool iou_gt(const float4& bi, float ai,
                                       const float4& bj, float aj) {
    float yy1 = fmaxf(bi.x, bj.x);
    float xx1 = fmaxf(bi.y, bj.y);
    float yy2 = fminf(bi.z, bj.z);
    float xx2 = fminf(bi.w, bj.w);
    float inter = fmaxf(yy2 - yy1, 0.f) * fmaxf(xx2 - xx1, 0.f);
    float iou = inter / (ai + aj - inter + EPSV);
    return iou > IOU_THR;
}

__device__ __forceinline__ u64 cs_keep(u64 v, u64 pv, int i, int j, int k) {
    bool lower   = ((i & j) == 0);
    bool desc    = ((i & k) == 0);
    bool keepmax = (desc == lower);
    u64 mx = v > pv ? v : pv;
    u64 mn = v > pv ? pv : v;
    return keepmax ? mx : mn;
}

__device__ __forceinline__ int wave_append(bool pred, int lane, int* cnt) {
    u64 bal = __ballot(pred);
    if (!bal) return -1;
    int tot = __popcll(bal);
    int fl  = __ffsll(bal) - 1;
    int base = 0;
    if (lane == fl) base = atomicAdd(cnt, tot);
    base = __shfl(base, fl, 64);
    return base + __popcll(bal & ((1ull << lane) - 1));
}

// ---------------- K1: per-slice histogram + speculative gather -------------
__global__ __launch_bounds__(256) void k1_hist_gather(
    const float4* __restrict__ score4,
    uint32_t* __restrict__ g_hist,       // [B*SL*NBINS], plain stores
    u64*      __restrict__ g_pairs,      // [B*SL*KBUF]
    int*      __restrict__ g_scnt,       // [B*SL], raw counts, plain stores
    int N)
{
    const int blk = blockIdx.x;
    const int b   = blk / SL;
    const int s   = blk % SL;
    const int tid = threadIdx.x;
    const int F4PB = N >> 2;
    const int F4PS = (F4PB + SL - 1) / SL;

    __shared__ uint32_t hist[NBINS];
    __shared__ u64 keybuf[KBUF];
    __shared__ int kcnt;

    for (int i = tid; i < NBINS; i += 256) hist[i] = 0u;
    if (tid == 0) kcnt = 0;
    __syncthreads();

    const float4* src = score4 + (size_t)b * F4PB;
    const int n0 = s * F4PS, n1 = min(n0 + F4PS, F4PB);
    for (int n = n0 + tid; n < n1; n += 256) {
        float4 v = src[n];
        float sv[4] = {v.x, v.y, v.z, v.w};
#pragma unroll
        for (int c = 0; c < 4; ++c) {
            int bn = bin_of(sv[c]);
            atomicAdd(&hist[bn], 1u);
            if (bn >= CONS) {
                int q = atomicAdd(&kcnt, 1);
                if (q < KBUF) keybuf[q] = make_key(sv[c], 4 * n + c, bn);
            }
        }
    }
    __syncthreads();

    uint32_t* gh = g_hist + ((size_t)b * SL + s) * NBINS;
    for (int i = tid; i < NBINS; i += 256) gh[i] = hist[i];

    if (tid == 0) g_scnt[b * SL + s] = kcnt;   // raw (may exceed KBUF)
    int lc = min(kcnt, KBUF);
    u64* gp = g_pairs + ((size_t)b * SL + s) * KBUF;
    for (int i = tid; i < lc; i += 256) gp[i] = keybuf[i];
}

// ---------------- K2: sum-hists + select + filter + pivot + sort -----------
__global__ __launch_bounds__(1024) void k2_sort(
    const float4* __restrict__ score4,
    const u64*  __restrict__ g_pairs,
    const int*  __restrict__ g_scnt,
    const uint32_t* __restrict__ g_hist,
    u64* __restrict__ g_sorted,
    int N)
{
    const int b    = blockIdx.x;
    const int tid  = threadIdx.x;
    const int lane = tid & 63;
    const int wv   = tid >> 6;

    __shared__ u64 pairs[SORTN];
    __shared__ u64 cand[CANDCAP];
    __shared__ uint32_t wtot[16];
    __shared__ int sh_bsel, sh_tprime, sh_cnt, sh_nc, sh_flag;
    __shared__ uint32_t sh_pivot;

    const int F4PB = N >> 2;

    // stage summed histogram into pairs region
    uint32_t* hist = (uint32_t*)pairs;
    {
        const uint32_t* gh = g_hist + (size_t)b * SL * NBINS;
#pragma unroll
        for (int h = 0; h < 2; ++h) {
            int i = tid + h * 1024;
            uint32_t acc = 0u;
#pragma unroll
            for (int s = 0; s < SL; ++s) acc += gh[(size_t)s * NBINS + i];
            hist[i] = acc;
        }
    }
    if (tid == 0) {
        sh_cnt = 0; sh_nc = 0;
        int f = 0;
#pragma unroll
        for (int s = 0; s < SL; ++s)
            if (g_scnt[b * SL + s] > KBUF) f = 1;
        sh_flag = f;
    }
    __syncthreads();

    // wave-shuffle suffix scan
    {
        const int i0 = wv * 128 + lane;
        const int i1 = i0 + 64;
        int h0 = (int)hist[i0];
        int h1 = (int)hist[i1];
        int s0 = h0, s1 = h1;
#pragma unroll
        for (int off = 1; off < 64; off <<= 1) {
            int t0 = __shfl_down(s0, off, 64);
            int t1 = __shfl_down(s1, off, 64);
            if (lane + off < 64) { s0 += t0; s1 += t1; }
        }
        int sum_h1 = __shfl(s1, 0, 64);
        if (lane == 0) wtot[wv] = (uint32_t)(__shfl(s0, 0, 64) + sum_h1);
        __syncthreads();
        int offtot = 0;
        for (int w2 = wv + 1; w2 < 16; ++w2) offtot += (int)wtot[w2];
        int S0 = s0 + sum_h1 + offtot;
        int S1 = s1 + offtot;
        if (S0 >= PRE && S0 - h0 < PRE) { sh_bsel = i0; sh_tprime = PRE - (S0 - h0); }
        if (S1 >= PRE && S1 - h1 < PRE) { sh_bsel = i1; sh_tprime = PRE - (S1 - h1); }
    }
    __syncthreads();
    const int bsel   = sh_bsel;
    const int tprime = sh_tprime;
    const bool flag  = (bsel < CONS) || sh_flag;
    __syncthreads();        // hist consumed; pairs writable

    if (!flag) {
        // gather from the 8 per-slice segments (order irrelevant: we sort)
        for (int s = 0; s < SL; ++s) {
            const int  cs = min(g_scnt[b * SL + s], KBUF);
            const u64* gp = g_pairs + ((size_t)b * SL + s) * KBUF;
            for (int i0 = 0; i0 < cs; i0 += 1024) {
                int i = i0 + tid;
                bool valid = (i < cs);
                u64 key = valid ? gp[i] : 0ull;
                int bn = (int)((key >> 20) & 0xFFFu);
                bool isP = valid && (bn > bsel);
                bool isC = valid && (bn == bsel);
                int sp = wave_append(isP, lane, &sh_cnt);
                if (isP && sp < SORTN) pairs[sp] = key;
                int sc = wave_append(isC, lane, &sh_nc);
                if (isC && sc < CANDCAP) cand[sc] = key;
            }
        }
    } else {
        // exact fallback: full re-gather from scores (rare)
        const float4* src = score4 + (size_t)b * F4PB;
        for (int n = tid; n < F4PB; n += 1024) {
            float4 v = src[n];
            float sv[4] = {v.x, v.y, v.z, v.w};
#pragma unroll
            for (int c = 0; c < 4; ++c) {
                int bn = bin_of(sv[c]);
                if (bn >= bsel) {
                    u64 key = make_key(sv[c], 4 * n + c, bn);
                    if (bn > bsel) {
                        int q = atomicAdd(&sh_cnt, 1);
                        if (q < SORTN) pairs[q] = key;
                    } else {
                        int t = atomicAdd(&sh_nc, 1);
                        if (t < CANDCAP) cand[t] = key;
                    }
                }
            }
        }
    }
    __syncthreads();

    // exact pivot among candidates (rank tprime on exact f32 bits)
    const int nc = min(sh_nc, CANDCAP);
    for (int i = tid; i < nc; i += 1024) {
        uint32_t vi = (uint32_t)(cand[i] >> 32);
        int g = 0, e = 0;
        for (int j = 0; j < nc; ++j) {
            uint32_t vj = (uint32_t)(cand[j] >> 32);
            g += (vj > vi);
            e += (vj == vi);
        }
        if (g < tprime && g + e >= tprime) sh_pivot = vi;
    }
    __syncthreads();
    const uint32_t pivot = sh_pivot;
    for (int i = tid; i < nc; i += 1024) {
        uint32_t vi = (uint32_t)(cand[i] >> 32);
        if (vi >= pivot) {
            int q = atomicAdd(&sh_cnt, 1);
            if (q < SORTN) pairs[q] = cand[i];
        }
    }
    __syncthreads();
    const int total = min(sh_cnt, SORTN);
    for (int q = total + tid; q < SORTN; q += 1024)
        pairs[q] = 0ull;
    __syncthreads();

    // bitonic sort in registers (2 elems/lane x 16 waves)
    {
        const int i0 = wv * 128 + lane;
        const int i1 = i0 + 64;
        u64 e0 = pairs[i0];
        u64 e1 = pairs[i1];
        for (int k = 2; k <= SORTN; k <<= 1) {
            for (int j = k >> 1; j > 0; j >>= 1) {
                if (j >= 128) {
                    pairs[i0] = e0;
                    pairs[i1] = e1;
                    __syncthreads();
                    u64 p0 = pairs[i0 ^ j];
                    u64 p1 = pairs[i1 ^ j];
                    __syncthreads();
                    e0 = cs_keep(e0, p0, i0, j, k);
                    e1 = cs_keep(e1, p1, i1, j, k);
                } else if (j == 64) {
                    u64 a = e0, c = e1;
                    e0 = cs_keep(a, c, i0, 64, k);
                    e1 = cs_keep(c, a, i1, 64, k);
                } else {
                    e0 = cs_keep(e0, __shfl_xor(e0, j, 64), i0, j, k);
                    e1 = cs_keep(e1, __shfl_xor(e1, j, 64), i1, j, k);
                }
            }
        }
        g_sorted[(size_t)b * SORTN + i0] = e0;
        g_sorted[(size_t)b * SORTN + i1] = e1;
    }
}

// ---------------- K3: decode sorted top-2000 -------------------------------
__global__ __launch_bounds__(256) void k3_decode(
    const float4* __restrict__ deltas,
    const float4* __restrict__ anchors,
    const u64*  __restrict__ g_sorted,
    float4* __restrict__ g_boxes,
    float*  __restrict__ g_area,
    int N)
{
    const int b   = blockIdx.x >> 2;
    const int s   = blockIdx.x & 3;
    const int tid = threadIdx.x;
    const int r0 = s * 512, r1 = min(r0 + 512, PRE);

    const float4* dl = deltas + (size_t)b * N;
    for (int r = r0 + tid; r < r1; r += 256) {
        u64 key = g_sorted[(size_t)b * SORTN + r];
        uint32_t idx = 0xFFFFFu - (uint32_t)(key & 0xFFFFFull);
        float4 bx = make_float4(0.f, 0.f, 0.f, 0.f);
        float  ar = 0.f;
        if (idx < (uint32_t)N) {
            float4 d  = dl[idx];
            float4 an = anchors[idx];
            float ah  = an.z - an.x;
            float aw  = an.w - an.y;
            float acy = an.x + 0.5f * ah;
            float acx = an.y + 0.5f * aw;
            float h   = expf(d.z) * ah;
            float w   = expf(d.w) * aw;
            float cy  = d.x * ah + acy;
            float cx  = d.y * aw + acx;
            float y1  = cy - 0.5f * h;
            float x1  = cx - 0.5f * w;
            bx = make_float4(y1, x1, y1 + h, x1 + w);
            ar = fmaxf(bx.z - bx.x, 0.f) * fmaxf(bx.w - bx.y, 0.f);
        }
        g_boxes[(size_t)b * PRE + r] = bx;
        g_area [(size_t)b * PRE + r] = ar;
    }
}

// ---------------- K4: suppression matrix [512][16] -------------------------
__global__ __launch_bounds__(256) void k4_supmat(
    const float4* __restrict__ g_boxes,
    const float*  __restrict__ g_area,
    uint32_t* __restrict__ g_supmat)
{
    const int b   = blockIdx.x >> 2;
    const int s   = blockIdx.x & 3;
    const int tid = threadIdx.x;

    __shared__ float4 box[TILE];
    __shared__ float  area[TILE];
    for (int i = tid; i < TILE; i += 256) {
        box[i]  = g_boxes[(size_t)b * PRE + i];
        area[i] = g_area [(size_t)b * PRE + i];
    }
    __syncthreads();

    for (int idx = tid; idx < 128 * 16; idx += 256) {
        int rl  = idx & 127;
        int w   = idx >> 7;              // wave-uniform
        int row = s * 128 + rl;
        int jbase = w << 5;
        float4 bi = box[row];
        float  ai = area[row];
        uint32_t bits = 0u;
        if (jbase + 31 > row) {
#pragma unroll
            for (int c = 0; c < 32; ++c) {
                int j = jbase + c;
                if (j > row && iou_gt(bi, ai, box[j], area[j]))
                    bits |= (1u << c);
            }
        }
        g_supmat[((size_t)b * TILE + row) * 16 + w] = bits;
    }
}

// ---------------- K5: chunked greedy sweep + output ------------------------
__global__ __launch_bounds__(256) void k5_sweep(
    const uint32_t* __restrict__ g_supmat,
    const float4* __restrict__ g_boxes,
    const float*  __restrict__ g_area,
    float4* __restrict__ out)
{
    const int b   = blockIdx.x;
    const int tid = threadIdx.x;

    __shared__ uint32_t sup[TILE][SSTR];
    __shared__ uint32_t kept[POST];
    __shared__ u64 sh_keepbits[TILE / 64];
    __shared__ uint32_t fmask[(PRE - TILE + 31) / 32];
    __shared__ int sh_kc;

    // stage supmat into padded LDS (uint2 chunks, 256 threads)
    {
        const uint2* gs = (const uint2*)(g_supmat + (size_t)b * TILE * 16);
        for (int idx = tid; idx < TILE * 8; idx += 256) {
            int row = idx >> 3, h = idx & 7;
            uint2 v = gs[idx];
            *(uint2*)&sup[row][2 * h] = v;
        }
    }
    __syncthreads();

    // wave-0 chunked greedy sweep (wave-uniform scalar resolve)
    if (tid < 64) {
        const int lane = tid;
        uint32_t removedw = 0u;          // lanes 0..15: removed word
        int kc = 0, nq = 0;
        for (int q = 0; q < TILE / 64; ++q) {
            const int cbase = q << 6;
            u64 rowchunk = *(const u64*)(&sup[cbase + lane][2 * q]);
            uint32_t rcl = (uint32_t)rowchunk;
            uint32_t rch = (uint32_t)(rowchunk >> 32);
            uint32_t rlo = (uint32_t)__builtin_amdgcn_readlane((int)removedw, 2 * q);
            uint32_t rhi = (uint32_t)__builtin_amdgcn_readlane((int)removedw, 2 * q + 1);
            u64 avail = ~(((u64)rhi << 32) | rlo);
            u64 keep = 0ull;
            while (avail) {
                int i = __ffsll(avail) - 1;
                keep |= (1ull << i);
                u64 row_i =
                    ((u64)(uint32_t)__builtin_amdgcn_readlane((int)rch, i) << 32) |
                    (uint32_t)__builtin_amdgcn_readlane((int)rcl, i);
                avail &= ~((1ull << i) | row_i);
            }
            if (lane == 0) sh_keepbits[q] = keep;
            kc += __popcll(keep);
            nq = q + 1;
            if (kc >= POST) break;
            u64 kb = keep;
            while (kb) {
                int c0 = __ffsll(kb) - 1; kb &= kb - 1;
                int c1 = c0, c2 = c0, c3 = c0;
                if (kb) { c1 = __ffsll(kb) - 1; kb &= kb - 1; }
                if (kb) { c2 = __ffsll(kb) - 1; kb &= kb - 1; }
                if (kb) { c3 = __ffsll(kb) - 1; kb &= kb - 1; }
                if (lane < 16) {
                    uint32_t a0 = sup[cbase + c0][lane];
                    uint32_t a1 = sup[cbase + c1][lane];
                    uint32_t a2 = sup[cbase + c2][lane];
                    uint32_t a3 = sup[cbase + c3][lane];
                    removedw |= (a0 | a1 | a2 | a3);
                }
            }
        }
        // compaction: kept[pos] in greedy order
        int base = 0;
        for (int q = 0; q < nq; ++q) {
            u64 kbq = sh_keepbits[q];
            int pos = base + __popcll(kbq & ((1ull << lane) - 1));
            if (((kbq >> lane) & 1ull) && pos < POST)
                kept[pos] = (uint32_t)(q * 64 + lane);
            base += __popcll(kbq);
        }
        if (lane == 0) sh_kc = min(kc, POST);
    }
    __syncthreads();
    int kc = sh_kc;

    // fallback beyond row 512 (exact; not taken on this data)
    if (kc < POST) {
        for (int w = tid; w < (PRE - TILE + 31) / 32; w += 256) fmask[w] = 0u;
        __syncthreads();
        for (int j = TILE + tid; j < PRE; j += 256) {
            float4 bj = g_boxes[(size_t)b * PRE + j];
            float  aj = g_area [(size_t)b * PRE + j];
            bool supd = false;
            for (int k = 0; k < kc; ++k) {
                int i = (int)kept[k];
                float4 bi = g_boxes[(size_t)b * PRE + i];
                float  ai = g_area [(size_t)b * PRE + i];
                if (iou_gt(bi, ai, bj, aj)) { supd = true; break; }
            }
            if (supd) atomicOr(&fmask[(j - TILE) >> 5], 1u << ((j - TILE) & 31));
        }
        __syncthreads();
        int i = TILE;
        while (i < PRE && kc < POST) {
            while (i < PRE && ((fmask[(i - TILE) >> 5] >> ((i - TILE) & 31)) & 1u)) ++i;
            if (i >= PRE) break;
            if (tid == 0) kept[kc] = (uint32_t)i;
            ++kc;
            if (kc >= POST) break;
            float4 bi = g_boxes[(size_t)b * PRE + i];
            float  ai = g_area [(size_t)b * PRE + i];
            for (int j = i + 1 + tid; j < PRE; j += 256) {
                float4 bj = g_boxes[(size_t)b * PRE + j];
                float  aj = g_area [(size_t)b * PRE + j];
                if (iou_gt(bi, ai, bj, aj))
                    atomicOr(&fmask[(j - TILE) >> 5], 1u << ((j - TILE) & 31));
            }
            ++i;
            __syncthreads();
        }
    }
    __syncthreads();

    // write clipped output
    float4* ob = out + (size_t)b * POST;
    for (int r = tid; r < POST; r += 256) {
        float4 o = make_float4(0.f, 0.f, 0.f, 0.f);
        if (r < kc) {
            float4 bx = g_boxes[(size_t)b * PRE + kept[r]];
            o.x = fminf(fmaxf(bx.x, 0.f), 1.f);
            o.y = fminf(fmaxf(bx.y, 0.f), 1.f);
            o.z = fminf(fmaxf(bx.z, 0.f), 1.f);
            o.w = fminf(fmaxf(bx.w, 0.f), 1.f);
        }
        ob[r] = o;
    }
}

extern "C" void kernel_launch(void* const* d_in, const int* in_sizes, int n_in,
                              void* d_out, int out_size, void* d_ws, size_t ws_size,
                              hipStream_t stream) {
    const float4* deltas  = (const float4*)d_in[0];
    const float*  labels  = (const float*)d_in[1];
    const float4* anchors = (const float4*)d_in[2];
    const float4* score4  = (const float4*)labels;
    float4*       outp    = (float4*)d_out;
    const int N = in_sizes[2] / 4;      // 90000
    const int B = in_sizes[1] / N;      // 64

    // workspace layout (16B-aligned chunks), no zero-init required anywhere:
    // boxes | pairs | sorted | supmat | area | hist | scnt
    char* ws = (char*)d_ws;
    const size_t SZ_BOXES  = (size_t)B * PRE * 16;
    const size_t SZ_PAIRS  = (size_t)B * SL * KBUF * 8;
    const size_t SZ_SORTED = (size_t)B * SORTN * 8;
    const size_t SZ_SUPMAT = (size_t)B * TILE * 16 * 4;
    const size_t SZ_AREA   = (size_t)B * PRE * 4;
    const size_t SZ_HIST   = (size_t)B * SL * NBINS * 4;
    float4*   g_boxes  = (float4*)ws;
    u64*      g_pairs  = (u64*)(ws + SZ_BOXES);
    u64*      g_sorted = (u64*)(ws + SZ_BOXES + SZ_PAIRS);
    uint32_t* g_supmat = (uint32_t*)(ws + SZ_BOXES + SZ_PAIRS + SZ_SORTED);
    float*    g_area   = (float*)(ws + SZ_BOXES + SZ_PAIRS + SZ_SORTED + SZ_SUPMAT);
    uint32_t* g_hist   = (uint32_t*)(ws + SZ_BOXES + SZ_PAIRS + SZ_SORTED + SZ_SUPMAT + SZ_AREA);
    int*      g_scnt   = (int*)((char*)g_hist + SZ_HIST);

    k1_hist_gather<<<B * SL, 256, 0, stream>>>(score4, g_hist, g_pairs,
                                               g_scnt, N);
    k2_sort<<<B, 1024, 0, stream>>>(score4, g_pairs, g_scnt, g_hist,
                                    g_sorted, N);
    k3_decode<<<B * 4, 256, 0, stream>>>(deltas, anchors, g_sorted,
                                         g_boxes, g_area, N);
    k4_supmat<<<B * 4, 256, 0, stream>>>(g_boxes, g_area, g_supmat);
    k5_sweep<<<B, 256, 0, stream>>>(g_supmat, g_boxes, g_area, outp);
}

// Round 9
// 112.976 us; speedup vs baseline: 1.1998x; 1.0389x over previous
//
#include <hip/hip_runtime.h>
#include <stdint.h>

// RPN RoI proposal, 5-kernel pipeline, no pre-zeroed state:
//  K1 (B*8 x 256): score pass -> per-slice histogram (plain stores) +
//     speculative key gather (bin>=CONS) into private per-slice segments.
//     key = flip(f32)<<32 | bin<<20 | (0xFFFFF-idx): u64 desc == lax.top_k.
//  K2 (B x 1024): sum slice hists; suffix-scan -> bsel/tprime + per-bin
//     segment bases; COUNTING-SCATTER keys to bin segments; exact pivot for
//     the bsel bin; per-wave in-register bitonic of each <=128 segment
//     (zero barriers) -> g_sorted. Fallback to full 2048 register bitonic
//     if bsel<CONS / slice overflow / any segment >128 (never taken here).
//  K3 (B*4 x 256): decode 512 ranks/block -> g_boxes, g_area.
//  K4 (B*4 x 256): suppression matrix rows -> g_supmat[512][16]; plus
//     transposed 64x64 DIAGONAL blocks -> g_supT (col j's in-chunk
//     suppressor word, for K5's ballot resolve).
//  K5 (B x 64): chunked greedy sweep: per 64-chunk, resolve via
//     ffs + ballot on per-lane column words (no readlane chain);
//     propagation to future chunks via 64-lane parallel global reads of
//     kept rows + 2 shfl_xor reduce. Early-exit at 300 kept; exact
//     barrier-loop fallback beyond row 512 (never taken); write [300,4].

#define PRE 2000
#define POST 300
#define TILE 512
#define IOU_THR 0.7f
#define EPSV 1e-8f
#define SORTN 2048
#define NBINS 2048
#define CANDCAP 512
#define CONS 1984
#define SL 8
#define KBUF 1536

typedef unsigned long long u64;

__device__ __forceinline__ uint32_t flip_f32(uint32_t b) {
    return b ^ ((uint32_t)((int32_t)b >> 31) | 0x80000000u);
}

__device__ __forceinline__ int bin_of(float s) {
    int bn = (int)(s * 2048.0f);
    return min(max(bn, 0), NBINS - 1);
}

__device__ __forceinline__ u64 make_key(float s, int idx, int bn) {
    uint32_t ub = flip_f32(__float_as_uint(s));
    return ((u64)ub << 32) | ((uint32_t)bn << 20) |
           (uint32_t)(0xFFFFF - idx);
}

__device__ __forceinline__ bool iou_gt(const float4& bi, float ai,
                                       const float4& bj, float aj) {
    float yy1 = fmaxf(bi.x, bj.x);
    float xx1 = fmaxf(bi.y, bj.y);
    float yy2 = fminf(bi.z, bj.z);
    float xx2 = fminf(bi.w, bj.w);
    float inter = fmaxf(yy2 - yy1, 0.f) * fmaxf(xx2 - xx1, 0.f);
    float iou = inter / (ai + aj - inter + EPSV);
    return iou > IOU_THR;
}

__device__ __forceinline__ u64 cs_keep(u64 v, u64 pv, int i, int j, int k) {
    bool lower   = ((i & j) == 0);
    bool desc    = ((i & k) == 0);
    bool keepmax = (desc == lower);
    u64 mx = v > pv ? v : pv;
    u64 mn = v > pv ? pv : v;
    return keepmax ? mx : mn;
}

// ---------------- K1: per-slice histogram + speculative gather -------------
__global__ __launch_bounds__(256) void k1_hist_gather(
    const float4* __restrict__ score4,
    uint32_t* __restrict__ g_hist,       // [B*SL*NBINS], plain stores
    u64*      __restrict__ g_pairs,      // [B*SL*KBUF]
    int*      __restrict__ g_scnt,       // [B*SL], raw counts
    int N)
{
    const int blk = blockIdx.x;
    const int b   = blk / SL;
    const int s   = blk % SL;
    const int tid = threadIdx.x;
    const int F4PB = N >> 2;
    const int F4PS = (F4PB + SL - 1) / SL;

    __shared__ uint32_t hist[NBINS];
    __shared__ u64 keybuf[KBUF];
    __shared__ int kcnt;

    for (int i = tid; i < NBINS; i += 256) hist[i] = 0u;
    if (tid == 0) kcnt = 0;
    __syncthreads();

    const float4* src = score4 + (size_t)b * F4PB;
    const int n0 = s * F4PS, n1 = min(n0 + F4PS, F4PB);
    for (int n = n0 + tid; n < n1; n += 256) {
        float4 v = src[n];
        float sv[4] = {v.x, v.y, v.z, v.w};
#pragma unroll
        for (int c = 0; c < 4; ++c) {
            int bn = bin_of(sv[c]);
            atomicAdd(&hist[bn], 1u);
            if (bn >= CONS) {
                int q = atomicAdd(&kcnt, 1);
                if (q < KBUF) keybuf[q] = make_key(sv[c], 4 * n + c, bn);
            }
        }
    }
    __syncthreads();

    uint32_t* gh = g_hist + ((size_t)b * SL + s) * NBINS;
    for (int i = tid; i < NBINS; i += 256) gh[i] = hist[i];

    if (tid == 0) g_scnt[b * SL + s] = kcnt;
    int lc = min(kcnt, KBUF);
    u64* gp = g_pairs + ((size_t)b * SL + s) * KBUF;
    for (int i = tid; i < lc; i += 256) gp[i] = keybuf[i];
}

// ---------------- K2: counting-scatter + segmented sort --------------------
__global__ __launch_bounds__(1024) void k2_sort(
    const float4* __restrict__ score4,
    const u64*  __restrict__ g_pairs,
    const int*  __restrict__ g_scnt,
    const uint32_t* __restrict__ g_hist,
    u64* __restrict__ g_sorted,
    int N)
{
    const int b    = blockIdx.x;
    const int tid  = threadIdx.x;
    const int lane = tid & 63;
    const int wv   = tid >> 6;

    __shared__ u64 pairs[SORTN];
    __shared__ u64 cand[CANDCAP];
    __shared__ uint32_t wtot[16];
    __shared__ int segbase[64];          // bins [CONS, 2048)
    __shared__ int segcnt[64];           // exact hist count per bin
    __shared__ uint32_t cur[64];         // scatter cursors
    __shared__ int sh_bsel, sh_tprime, sh_cnt, sh_nc, sh_flag, sh_big;
    __shared__ uint32_t sh_pivot;

    const int F4PB = N >> 2;

    // stage summed histogram into pairs region; init
    uint32_t* hist = (uint32_t*)pairs;
    {
        const uint32_t* gh = g_hist + (size_t)b * SL * NBINS;
#pragma unroll
        for (int h = 0; h < 2; ++h) {
            int i = tid + h * 1024;
            uint32_t acc = 0u;
#pragma unroll
            for (int s = 0; s < SL; ++s) acc += gh[(size_t)s * NBINS + i];
            hist[i] = acc;
        }
    }
    if (tid < 64) cur[tid] = 0u;
    if (tid == 0) {
        sh_cnt = 0; sh_nc = 0; sh_big = 0;
        int f = 0;
#pragma unroll
        for (int s = 0; s < SL; ++s)
            if (g_scnt[b * SL + s] > KBUF) f = 1;
        sh_flag = f;
    }
    __syncthreads();

    // wave-shuffle suffix scan; persists per-bin bases for bins >= CONS
    {
        const int i0 = wv * 128 + lane;
        const int i1 = i0 + 64;
        int h0 = (int)hist[i0];
        int h1 = (int)hist[i1];
        int s0 = h0, s1 = h1;
#pragma unroll
        for (int off = 1; off < 64; off <<= 1) {
            int t0 = __shfl_down(s0, off, 64);
            int t1 = __shfl_down(s1, off, 64);
            if (lane + off < 64) { s0 += t0; s1 += t1; }
        }
        int sum_h1 = __shfl(s1, 0, 64);
        if (lane == 0) wtot[wv] = (uint32_t)(__shfl(s0, 0, 64) + sum_h1);
        __syncthreads();
        int offtot = 0;
        for (int w2 = wv + 1; w2 < 16; ++w2) offtot += (int)wtot[w2];
        int S0 = s0 + sum_h1 + offtot;   // S(i0) = #{bin >= i0}
        int S1 = s1 + offtot;            // S(i1)
        if (S0 >= PRE && S0 - h0 < PRE) { sh_bsel = i0; sh_tprime = PRE - (S0 - h0); }
        if (S1 >= PRE && S1 - h1 < PRE) { sh_bsel = i1; sh_tprime = PRE - (S1 - h1); }
        if (i1 >= CONS) {                // wave 15 covers [1984, 2048)
            segbase[i1 - CONS] = S1 - h1;    // = S(i1+1)
            segcnt [i1 - CONS] = h1;
        }
    }
    __syncthreads();
    const int bsel   = sh_bsel;
    const int tprime = sh_tprime;
    bool flag = (bsel < CONS) || sh_flag;
    if (!flag && segcnt[bsel - CONS] > CANDCAP) flag = true;
    __syncthreads();        // hist consumed; pairs writable

    if (!flag) {
        // ---- counting-scatter: bin>bsel -> its segment; ==bsel -> cand ----
        for (int s = 0; s < SL; ++s) {
            const int  cs = min(g_scnt[b * SL + s], KBUF);
            const u64* gp = g_pairs + ((size_t)b * SL + s) * KBUF;
            for (int i = tid; i < cs; i += 1024) {
                u64 key = gp[i];
                int bn = (int)((key >> 20) & 0xFFFu);
                if (bn > bsel) {
                    int c = (int)atomicAdd(&cur[bn - CONS], 1u);
                    pairs[segbase[bn - CONS] + c] = key;
                } else if (bn == bsel) {
                    int t = atomicAdd(&sh_nc, 1);
                    if (t < CANDCAP) cand[t] = key;
                }
            }
        }
        __syncthreads();
        // ---- exact pivot among bsel-bin candidates ----
        const int nc = min(sh_nc, CANDCAP);   // == segcnt[bsel] (guarded)
        for (int i = tid; i < nc; i += 1024) {
            uint32_t vi = (uint32_t)(cand[i] >> 32);
            int g = 0, e = 0;
            for (int j = 0; j < nc; ++j) {
                uint32_t vj = (uint32_t)(cand[j] >> 32);
                g += (vj > vi);
                e += (vj == vi);
            }
            if (g < tprime && g + e >= tprime) sh_pivot = vi;
        }
        __syncthreads();
        const uint32_t pivot = sh_pivot;
        for (int i = tid; i < nc; i += 1024) {
            uint32_t vi = (uint32_t)(cand[i] >> 32);
            if (vi >= pivot) {
                int c = (int)atomicAdd(&cur[bsel - CONS], 1u);
                pairs[segbase[bsel - CONS] + c] = cand[i];
            }
        }
        __syncthreads();
        const int total = segbase[bsel - CONS] + (int)cur[bsel - CONS];
        for (int q = total + tid; q < SORTN; q += 1024) pairs[q] = 0ull;
        if (tid < 64 && (int)cur[tid] > 128) sh_big = 1;
        __syncthreads();
    } else {
        // ---- exact fallback: full re-gather (rare) ----
        const float4* src = score4 + (size_t)b * F4PB;
        for (int n = tid; n < F4PB; n += 1024) {
            float4 v = src[n];
            float sv[4] = {v.x, v.y, v.z, v.w};
#pragma unroll
            for (int c = 0; c < 4; ++c) {
                int bn = bin_of(sv[c]);
                if (bn >= bsel) {
                    u64 key = make_key(sv[c], 4 * n + c, bn);
                    if (bn > bsel) {
                        int q = atomicAdd(&sh_cnt, 1);
                        if (q < SORTN) pairs[q] = key;
                    } else {
                        int t = atomicAdd(&sh_nc, 1);
                        if (t < CANDCAP) cand[t] = key;
                    }
                }
            }
        }
        __syncthreads();
        const int nc = min(sh_nc, CANDCAP);
        for (int i = tid; i < nc; i += 1024) {
            uint32_t vi = (uint32_t)(cand[i] >> 32);
            int g = 0, e = 0;
            for (int j = 0; j < nc; ++j) {
                uint32_t vj = (uint32_t)(cand[j] >> 32);
                g += (vj > vi);
                e += (vj == vi);
            }
            if (g < tprime && g + e >= tprime) sh_pivot = vi;
        }
        __syncthreads();
        const uint32_t pivot = sh_pivot;
        for (int i = tid; i < nc; i += 1024) {
            uint32_t vi = (uint32_t)(cand[i] >> 32);
            if (vi >= pivot) {
                int q = atomicAdd(&sh_cnt, 1);
                if (q < SORTN) pairs[q] = cand[i];
            }
        }
        __syncthreads();
        const int total = min(sh_cnt, SORTN);
        for (int q = total + tid; q < SORTN; q += 1024) pairs[q] = 0ull;
        if (tid == 0) sh_big = 1;        // route to full bitonic
        __syncthreads();
    }

    if (!sh_big) {
        // ---- per-wave segment sorts (zero barriers) ----
        for (int sgi = wv; sgi < 64; sgi += 16) {
            int n = (int)cur[sgi];
            if (n <= 0) continue;
            int base = segbase[sgi];
            if (n <= 64) {
                u64 e = (lane < n) ? pairs[base + lane] : 0ull;
#pragma unroll
                for (int k = 2; k <= 64; k <<= 1)
                    for (int j = k >> 1; j > 0; j >>= 1)
                        e = cs_keep(e, __shfl_xor(e, j, 64), lane, j, k);
                if (lane < n) pairs[base + lane] = e;
            } else {                     // 65..128
                u64 e0 = (lane < n) ? pairs[base + lane] : 0ull;
                u64 e1 = (lane + 64 < n) ? pairs[base + lane + 64] : 0ull;
#pragma unroll
                for (int k = 2; k <= 128; k <<= 1) {
                    for (int j = k >> 1; j > 0; j >>= 1) {
                        if (j == 64) {
                            u64 a = e0, c = e1;
                            e0 = cs_keep(a, c, lane, 64, k);
                            e1 = cs_keep(c, a, lane + 64, 64, k);
                        } else {
                            e0 = cs_keep(e0, __shfl_xor(e0, j, 64), lane, j, k);
                            e1 = cs_keep(e1, __shfl_xor(e1, j, 64), lane + 64, j, k);
                        }
                    }
                }
                if (lane < n) pairs[base + lane] = e0;
                if (lane + 64 < n) pairs[base + lane + 64] = e1;
            }
        }
        __syncthreads();
        g_sorted[(size_t)b * SORTN + tid]        = pairs[tid];
        g_sorted[(size_t)b * SORTN + tid + 1024] = pairs[tid + 1024];
    } else {
        // ---- full register bitonic (2 elems/lane x 16 waves) ----
        const int i0 = wv * 128 + lane;
        const int i1 = i0 + 64;
        u64 e0 = pairs[i0];
        u64 e1 = pairs[i1];
        for (int k = 2; k <= SORTN; k <<= 1) {
            for (int j = k >> 1; j > 0; j >>= 1) {
                if (j >= 128) {
                    pairs[i0] = e0;
                    pairs[i1] = e1;
                    __syncthreads();
                    u64 p0 = pairs[i0 ^ j];
                    u64 p1 = pairs[i1 ^ j];
                    __syncthreads();
                    e0 = cs_keep(e0, p0, i0, j, k);
                    e1 = cs_keep(e1, p1, i1, j, k);
                } else if (j == 64) {
                    u64 a = e0, c = e1;
                    e0 = cs_keep(a, c, i0, 64, k);
                    e1 = cs_keep(c, a, i1, 64, k);
                } else {
                    e0 = cs_keep(e0, __shfl_xor(e0, j, 64), i0, j, k);
                    e1 = cs_keep(e1, __shfl_xor(e1, j, 64), i1, j, k);
                }
            }
        }
        g_sorted[(size_t)b * SORTN + i0] = e0;
        g_sorted[(size_t)b * SORTN + i1] = e1;
    }
}

// ---------------- K3: decode sorted top-2000 -------------------------------
__global__ __launch_bounds__(256) void k3_decode(
    const float4* __restrict__ deltas,
    const float4* __restrict__ anchors,
    const u64*  __restrict__ g_sorted,
    float4* __restrict__ g_boxes,
    float*  __restrict__ g_area,
    int N)
{
    const int b   = blockIdx.x >> 2;
    const int s   = blockIdx.x & 3;
    const int tid = threadIdx.x;
    const int r0 = s * 512, r1 = min(r0 + 512, PRE);

    const float4* dl = deltas + (size_t)b * N;
    for (int r = r0 + tid; r < r1; r += 256) {
        u64 key = g_sorted[(size_t)b * SORTN + r];
        uint32_t idx = 0xFFFFFu - (uint32_t)(key & 0xFFFFFull);
        float4 bx = make_float4(0.f, 0.f, 0.f, 0.f);
        float  ar = 0.f;
        if (idx < (uint32_t)N) {
            float4 d  = dl[idx];
            float4 an = anchors[idx];
            float ah  = an.z - an.x;
            float aw  = an.w - an.y;
            float acy = an.x + 0.5f * ah;
            float acx = an.y + 0.5f * aw;
            float h   = expf(d.z) * ah;
            float w   = expf(d.w) * aw;
            float cy  = d.x * ah + acy;
            float cx  = d.y * aw + acx;
            float y1  = cy - 0.5f * h;
            float x1  = cx - 0.5f * w;
            bx = make_float4(y1, x1, y1 + h, x1 + w);
            ar = fmaxf(bx.z - bx.x, 0.f) * fmaxf(bx.w - bx.y, 0.f);
        }
        g_boxes[(size_t)b * PRE + r] = bx;
        g_area [(size_t)b * PRE + r] = ar;
    }
}

// ---------------- K4: suppression matrix + transposed diag blocks ----------
__global__ __launch_bounds__(256) void k4_supmat(
    const float4* __restrict__ g_boxes,
    const float*  __restrict__ g_area,
    uint32_t* __restrict__ g_supmat,     // [B*512*16] row-major
    uint32_t* __restrict__ g_supT)       // [B*512*2]  diag col-words
{
    const int b   = blockIdx.x >> 2;
    const int s   = blockIdx.x & 3;
    const int tid = threadIdx.x;

    __shared__ float4 box[TILE];
    __shared__ float  area[TILE];
    for (int i = tid; i < TILE; i += 256) {
        box[i]  = g_boxes[(size_t)b * PRE + i];
        area[i] = g_area [(size_t)b * PRE + i];
    }
    __syncthreads();

    // normal rows [s*128, s*128+128) x 16 words
    for (int idx = tid; idx < 128 * 16; idx += 256) {
        int rl  = idx & 127;
        int w   = idx >> 7;              // wave-uniform
        int row = s * 128 + rl;
        int jbase = w << 5;
        float4 bi = box[row];
        float  ai = area[row];
        uint32_t bits = 0u;
        if (jbase + 31 > row) {
#pragma unroll
            for (int c = 0; c < 32; ++c) {
                int j = jbase + c;
                if (j > row && iou_gt(bi, ai, box[j], area[j]))
                    bits |= (1u << c);
            }
        }
        g_supmat[((size_t)b * TILE + row) * 16 + w] = bits;
    }

    // transposed diagonal blocks for chunks 2s, 2s+1 (one task per thread):
    // word (col C, half w2): bit c = row R=q*64+w2*32+c suppresses C (R<C)
    {
        int t  = tid;
        int q  = 2 * s + (t >> 7);
        int j  = (t >> 1) & 63;
        int w2 = t & 1;
        int C  = q * 64 + j;
        float4 bc = box[C];
        float  ac = area[C];
        uint32_t bits = 0u;
#pragma unroll
        for (int c = 0; c < 32; ++c) {
            int R = q * 64 + w2 * 32 + c;
            if (R < C && iou_gt(box[R], area[R], bc, ac))
                bits |= (1u << c);
        }
        g_supT[((size_t)b * TILE + C) * 2 + w2] = bits;
    }
}

// ---------------- K5: ballot-resolve chunked greedy sweep ------------------
__global__ __launch_bounds__(64) void k5_sweep(
    const uint32_t* __restrict__ g_supmat,
    const u64*    __restrict__ g_supT64,   // [B*512] diag col-words
    const float4* __restrict__ g_boxes,
    const float*  __restrict__ g_area,
    float4* __restrict__ out)
{
    const int b    = blockIdx.x;
    const int lane = threadIdx.x;

    __shared__ uint32_t kept[POST];
    __shared__ u64 sh_keepbits[TILE / 64];
    __shared__ uint32_t fmask[(PRE - TILE + 31) / 32];
    __shared__ int sh_kc;

    const u64* tdbase = g_supT64 + (size_t)b * TILE;

    uint32_t removedw = 0u;              // lanes 0..15: removed word
    int kc = 0, nq = 0;
    u64 cw_cur = tdbase[lane];           // chunk 0 col-word
    for (int q = 0; q < TILE / 64; ++q) {
        u64 cw_next = (q < TILE / 64 - 1) ? tdbase[(q + 1) * 64 + lane] : 0ull;
        const int cbase = q << 6;
        uint32_t rlo = (uint32_t)__builtin_amdgcn_readlane((int)removedw, 2 * q);
        uint32_t rhi = (uint32_t)__builtin_amdgcn_readlane((int)removedw, 2 * q + 1);
        u64 avail = ~(((u64)rhi << 32) | rlo);
        u64 K = 0ull;
        while (avail) {                  // ballot-based greedy resolve
            int i = __ffsll((long long)avail) - 1;
            K |= (1ull << i);
            u64 supp = __ballot(((cw_cur >> i) & 1ull) != 0ull);
            avail &= ~(supp | (1ull << i));
        }
        if (lane == 0) sh_keepbits[q] = K;
        kc += __popcll(K);
        nq = q + 1;
        if (kc >= POST) break;
        // wide propagation: lane = w + 16*g covers 16 words x 4 row-groups
        if (K) {
            const int w = lane & 15;
            const int g = lane >> 4;
            const uint32_t* gs =
                g_supmat + ((size_t)b * TILE + cbase + g * 16) * 16 + w;
            uint32_t acc = 0u;
#pragma unroll
            for (int r = 0; r < 16; ++r)
                if ((K >> (g * 16 + r)) & 1ull) acc |= gs[(size_t)r * 16];
            acc |= (uint32_t)__shfl_xor((int)acc, 16, 64);
            acc |= (uint32_t)__shfl_xor((int)acc, 32, 64);
            if (lane < 16) removedw |= acc;
        }
        cw_cur = cw_next;
    }
    // compaction: kept[pos] in greedy order
    {
        int base = 0;
        for (int q = 0; q < nq; ++q) {
            u64 kbq = sh_keepbits[q];
            int pos = base + __popcll(kbq & ((1ull << lane) - 1));
            if (((kbq >> lane) & 1ull) && pos < POST)
                kept[pos] = (uint32_t)(q * 64 + lane);
            base += __popcll(kbq);
        }
        if (lane == 0) sh_kc = min(kc, POST);
    }
    __syncthreads();
    int kcf = sh_kc;

    // fallback beyond row 512 (exact; not taken on this data)
    if (kcf < POST) {
        for (int w = lane; w < (PRE - TILE + 31) / 32; w += 64) fmask[w] = 0u;
        __syncthreads();
        for (int j = TILE + lane; j < PRE; j += 64) {
            float4 bj = g_boxes[(size_t)b * PRE + j];
            float  aj = g_area [(size_t)b * PRE + j];
            bool supd = false;
            for (int k = 0; k < kcf; ++k) {
                int i = (int)kept[k];
                float4 bi = g_boxes[(size_t)b * PRE + i];
                float  ai = g_area [(size_t)b * PRE + i];
                if (iou_gt(bi, ai, bj, aj)) { supd = true; break; }
            }
            if (supd) atomicOr(&fmask[(j - TILE) >> 5], 1u << ((j - TILE) & 31));
        }
        __syncthreads();
        int i = TILE;
        while (i < PRE && kcf < POST) {
            while (i < PRE && ((fmask[(i - TILE) >> 5] >> ((i - TILE) & 31)) & 1u)) ++i;
            if (i >= PRE) break;
            if (lane == 0) kept[kcf] = (uint32_t)i;
            ++kcf;
            if (kcf >= POST) break;
            float4 bi = g_boxes[(size_t)b * PRE + i];
            float  ai = g_area [(size_t)b * PRE + i];
            for (int j = i + 1 + lane; j < PRE; j += 64) {
                float4 bj = g_boxes[(size_t)b * PRE + j];
                float  aj = g_area [(size_t)b * PRE + j];
                if (iou_gt(bi, ai, bj, aj))
                    atomicOr(&fmask[(j - TILE) >> 5], 1u << ((j - TILE) & 31));
            }
            ++i;
            __syncthreads();
        }
    }
    __syncthreads();

    // write clipped output
    float4* ob = out + (size_t)b * POST;
    for (int r = lane; r < POST; r += 64) {
        float4 o = make_float4(0.f, 0.f, 0.f, 0.f);
        if (r < kcf) {
            float4 bx = g_boxes[(size_t)b * PRE + kept[r]];
            o.x = fminf(fmaxf(bx.x, 0.f), 1.f);
            o.y = fminf(fmaxf(bx.y, 0.f), 1.f);
            o.z = fminf(fmaxf(bx.z, 0.f), 1.f);
            o.w = fminf(fmaxf(bx.w, 0.f), 1.f);
        }
        ob[r] = o;
    }
}

extern "C" void kernel_launch(void* const* d_in, const int* in_sizes, int n_in,
                              void* d_out, int out_size, void* d_ws, size_t ws_size,
                              hipStream_t stream) {
    const float4* deltas  = (const float4*)d_in[0];
    const float*  labels  = (const float*)d_in[1];
    const float4* anchors = (const float4*)d_in[2];
    const float4* score4  = (const float4*)labels;
    float4*       outp    = (float4*)d_out;
    const int N = in_sizes[2] / 4;      // 90000
    const int B = in_sizes[1] / N;      // 64

    // workspace (16B-aligned chunks), no zero-init required anywhere:
    // boxes | pairs | sorted | supmat | supT | area | hist | scnt
    char* ws = (char*)d_ws;
    const size_t SZ_BOXES  = (size_t)B * PRE * 16;
    const size_t SZ_PAIRS  = (size_t)B * SL * KBUF * 8;
    const size_t SZ_SORTED = (size_t)B * SORTN * 8;
    const size_t SZ_SUPMAT = (size_t)B * TILE * 16 * 4;
    const size_t SZ_SUPT   = (size_t)B * TILE * 8;
    const size_t SZ_AREA   = (size_t)B * PRE * 4;
    const size_t SZ_HIST   = (size_t)B * SL * NBINS * 4;
    float4*   g_boxes  = (float4*)ws;
    u64*      g_pairs  = (u64*)(ws + SZ_BOXES);
    u64*      g_sorted = (u64*)(ws + SZ_BOXES + SZ_PAIRS);
    uint32_t* g_supmat = (uint32_t*)(ws + SZ_BOXES + SZ_PAIRS + SZ_SORTED);
    uint32_t* g_supT   = (uint32_t*)(ws + SZ_BOXES + SZ_PAIRS + SZ_SORTED + SZ_SUPMAT);
    float*    g_area   = (float*)(ws + SZ_BOXES + SZ_PAIRS + SZ_SORTED + SZ_SUPMAT + SZ_SUPT);
    uint32_t* g_hist   = (uint32_t*)(ws + SZ_BOXES + SZ_PAIRS + SZ_SORTED + SZ_SUPMAT + SZ_SUPT + SZ_AREA);
    int*      g_scnt   = (int*)((char*)g_hist + SZ_HIST);

    k1_hist_gather<<<B * SL, 256, 0, stream>>>(score4, g_hist, g_pairs,
                                               g_scnt, N);
    k2_sort<<<B, 1024, 0, stream>>>(score4, g_pairs, g_scnt, g_hist,
                                    g_sorted, N);
    k3_decode<<<B * 4, 256, 0, stream>>>(deltas, anchors, g_sorted,
                                         g_boxes, g_area, N);
    k4_supmat<<<B * 4, 256, 0, stream>>>(g_boxes, g_area, g_supmat, g_supT);
    k5_sweep<<<B, 64, 0, stream>>>(g_supmat, (const u64*)g_supT,
                                   g_boxes, g_area, outp);
}

// Round 10
// 93.062 us; speedup vs baseline: 1.4566x; 1.2140x over previous
//
#include <hip/hip_runtime.h>
#include <stdint.h>

// RPN RoI proposal, 5-kernel pipeline, no pre-zeroed state:
//  K1 (B*8 x 256): score pass -> per-slice histogram (plain stores) +
//     speculative key gather (bin>=CONS) into private per-slice segments.
//     key = flip(f32)<<32 | bin<<20 | (0xFFFFF-idx): u64 desc == lax.top_k.
//  K2 (B x 1024): sum slice hists; suffix-scan -> bsel/tprime + per-bin
//     segment bases; counting-scatter to bin segments; exact pivot for the
//     bsel bin; per-wave in-register bitonic of each <=128 segment ->
//     g_sorted. Full-bitonic fallback (never taken here).
//  K3 (B*4 x 256): decode 512 ranks/block -> g_boxes, g_area.
//  K4 (B*16 x 256): suppression matrix. R10: 4 blocks/CU (16 waves/CU for
//     latency hiding -- R9 had 1 wave/SIMD, 87% stall), branchless inner
//     loop (batchable LDS loads), areas recomputed inline (no area[] LDS
//     reads). Rows 32/block x 16 words; blocks s<8 also emit the
//     transposed 64x64 diagonal col-words g_supT for K5's ballot resolve.
//  K5 (B x 64): chunked greedy sweep: per 64-chunk ffs+ballot resolve on
//     per-lane diag col-words; propagation to future chunks via 64-lane
//     parallel global reads + 2 shfl_xor. Early-exit at 300 kept; exact
//     barrier-loop fallback beyond row 512 (never taken); write [300,4].

#define PRE 2000
#define POST 300
#define TILE 512
#define IOU_THR 0.7f
#define EPSV 1e-8f
#define SORTN 2048
#define NBINS 2048
#define CANDCAP 512
#define CONS 1984
#define SL 8
#define KBUF 1536

typedef unsigned long long u64;

__device__ __forceinline__ uint32_t flip_f32(uint32_t b) {
    return b ^ ((uint32_t)((int32_t)b >> 31) | 0x80000000u);
}

__device__ __forceinline__ int bin_of(float s) {
    int bn = (int)(s * 2048.0f);
    return min(max(bn, 0), NBINS - 1);
}

__device__ __forceinline__ u64 make_key(float s, int idx, int bn) {
    uint32_t ub = flip_f32(__float_as_uint(s));
    return ((u64)ub << 32) | ((uint32_t)bn << 20) |
           (uint32_t)(0xFFFFF - idx);
}

__device__ __forceinline__ bool iou_gt(const float4& bi, float ai,
                                       const float4& bj, float aj) {
    float yy1 = fmaxf(bi.x, bj.x);
    float xx1 = fmaxf(bi.y, bj.y);
    float yy2 = fminf(bi.z, bj.z);
    float xx2 = fminf(bi.w, bj.w);
    float inter = fmaxf(yy2 - yy1, 0.f) * fmaxf(xx2 - xx1, 0.f);
    float iou = inter / (ai + aj - inter + EPSV);
    return iou > IOU_THR;
}

__device__ __forceinline__ float area_of(const float4& bx) {
    // identical expression to K3's g_area computation -> bit-exact
    return fmaxf(bx.z - bx.x, 0.f) * fmaxf(bx.w - bx.y, 0.f);
}

__device__ __forceinline__ u64 cs_keep(u64 v, u64 pv, int i, int j, int k) {
    bool lower   = ((i & j) == 0);
    bool desc    = ((i & k) == 0);
    bool keepmax = (desc == lower);
    u64 mx = v > pv ? v : pv;
    u64 mn = v > pv ? pv : v;
    return keepmax ? mx : mn;
}

// ---------------- K1: per-slice histogram + speculative gather -------------
__global__ __launch_bounds__(256) void k1_hist_gather(
    const float4* __restrict__ score4,
    uint32_t* __restrict__ g_hist,       // [B*SL*NBINS], plain stores
    u64*      __restrict__ g_pairs,      // [B*SL*KBUF]
    int*      __restrict__ g_scnt,       // [B*SL], raw counts
    int N)
{
    const int blk = blockIdx.x;
    const int b   = blk / SL;
    const int s   = blk % SL;
    const int tid = threadIdx.x;
    const int F4PB = N >> 2;
    const int F4PS = (F4PB + SL - 1) / SL;

    __shared__ uint32_t hist[NBINS];
    __shared__ u64 keybuf[KBUF];
    __shared__ int kcnt;

    for (int i = tid; i < NBINS; i += 256) hist[i] = 0u;
    if (tid == 0) kcnt = 0;
    __syncthreads();

    const float4* src = score4 + (size_t)b * F4PB;
    const int n0 = s * F4PS, n1 = min(n0 + F4PS, F4PB);
    for (int n = n0 + tid; n < n1; n += 256) {
        float4 v = src[n];
        float sv[4] = {v.x, v.y, v.z, v.w};
#pragma unroll
        for (int c = 0; c < 4; ++c) {
            int bn = bin_of(sv[c]);
            atomicAdd(&hist[bn], 1u);
            if (bn >= CONS) {
                int q = atomicAdd(&kcnt, 1);
                if (q < KBUF) keybuf[q] = make_key(sv[c], 4 * n + c, bn);
            }
        }
    }
    __syncthreads();

    uint32_t* gh = g_hist + ((size_t)b * SL + s) * NBINS;
    for (int i = tid; i < NBINS; i += 256) gh[i] = hist[i];

    if (tid == 0) g_scnt[b * SL + s] = kcnt;
    int lc = min(kcnt, KBUF);
    u64* gp = g_pairs + ((size_t)b * SL + s) * KBUF;
    for (int i = tid; i < lc; i += 256) gp[i] = keybuf[i];
}

// ---------------- K2: counting-scatter + segmented sort --------------------
__global__ __launch_bounds__(1024) void k2_sort(
    const float4* __restrict__ score4,
    const u64*  __restrict__ g_pairs,
    const int*  __restrict__ g_scnt,
    const uint32_t* __restrict__ g_hist,
    u64* __restrict__ g_sorted,
    int N)
{
    const int b    = blockIdx.x;
    const int tid  = threadIdx.x;
    const int lane = tid & 63;
    const int wv   = tid >> 6;

    __shared__ u64 pairs[SORTN];
    __shared__ u64 cand[CANDCAP];
    __shared__ uint32_t wtot[16];
    __shared__ int segbase[64];          // bins [CONS, 2048)
    __shared__ int segcnt[64];
    __shared__ uint32_t cur[64];         // scatter cursors
    __shared__ int sh_bsel, sh_tprime, sh_cnt, sh_nc, sh_flag, sh_big;
    __shared__ uint32_t sh_pivot;

    const int F4PB = N >> 2;

    uint32_t* hist = (uint32_t*)pairs;
    {
        const uint32_t* gh = g_hist + (size_t)b * SL * NBINS;
#pragma unroll
        for (int h = 0; h < 2; ++h) {
            int i = tid + h * 1024;
            uint32_t acc = 0u;
#pragma unroll
            for (int s = 0; s < SL; ++s) acc += gh[(size_t)s * NBINS + i];
            hist[i] = acc;
        }
    }
    if (tid < 64) cur[tid] = 0u;
    if (tid == 0) {
        sh_cnt = 0; sh_nc = 0; sh_big = 0;
        int f = 0;
#pragma unroll
        for (int s = 0; s < SL; ++s)
            if (g_scnt[b * SL + s] > KBUF) f = 1;
        sh_flag = f;
    }
    __syncthreads();

    // wave-shuffle suffix scan; persists per-bin bases for bins >= CONS
    {
        const int i0 = wv * 128 + lane;
        const int i1 = i0 + 64;
        int h0 = (int)hist[i0];
        int h1 = (int)hist[i1];
        int s0 = h0, s1 = h1;
#pragma unroll
        for (int off = 1; off < 64; off <<= 1) {
            int t0 = __shfl_down(s0, off, 64);
            int t1 = __shfl_down(s1, off, 64);
            if (lane + off < 64) { s0 += t0; s1 += t1; }
        }
        int sum_h1 = __shfl(s1, 0, 64);
        if (lane == 0) wtot[wv] = (uint32_t)(__shfl(s0, 0, 64) + sum_h1);
        __syncthreads();
        int offtot = 0;
        for (int w2 = wv + 1; w2 < 16; ++w2) offtot += (int)wtot[w2];
        int S0 = s0 + sum_h1 + offtot;
        int S1 = s1 + offtot;
        if (S0 >= PRE && S0 - h0 < PRE) { sh_bsel = i0; sh_tprime = PRE - (S0 - h0); }
        if (S1 >= PRE && S1 - h1 < PRE) { sh_bsel = i1; sh_tprime = PRE - (S1 - h1); }
        if (i1 >= CONS) {
            segbase[i1 - CONS] = S1 - h1;
            segcnt [i1 - CONS] = h1;
        }
    }
    __syncthreads();
    const int bsel   = sh_bsel;
    const int tprime = sh_tprime;
    bool flag = (bsel < CONS) || sh_flag;
    if (!flag && segcnt[bsel - CONS] > CANDCAP) flag = true;
    __syncthreads();

    if (!flag) {
        for (int s = 0; s < SL; ++s) {
            const int  cs = min(g_scnt[b * SL + s], KBUF);
            const u64* gp = g_pairs + ((size_t)b * SL + s) * KBUF;
            for (int i = tid; i < cs; i += 1024) {
                u64 key = gp[i];
                int bn = (int)((key >> 20) & 0xFFFu);
                if (bn > bsel) {
                    int c = (int)atomicAdd(&cur[bn - CONS], 1u);
                    pairs[segbase[bn - CONS] + c] = key;
                } else if (bn == bsel) {
                    int t = atomicAdd(&sh_nc, 1);
                    if (t < CANDCAP) cand[t] = key;
                }
            }
        }
        __syncthreads();
        const int nc = min(sh_nc, CANDCAP);
        for (int i = tid; i < nc; i += 1024) {
            uint32_t vi = (uint32_t)(cand[i] >> 32);
            int g = 0, e = 0;
            for (int j = 0; j < nc; ++j) {
                uint32_t vj = (uint32_t)(cand[j] >> 32);
                g += (vj > vi);
                e += (vj == vi);
            }
            if (g < tprime && g + e >= tprime) sh_pivot = vi;
        }
        __syncthreads();
        const uint32_t pivot = sh_pivot;
        for (int i = tid; i < nc; i += 1024) {
            uint32_t vi = (uint32_t)(cand[i] >> 32);
            if (vi >= pivot) {
                int c = (int)atomicAdd(&cur[bsel - CONS], 1u);
                pairs[segbase[bsel - CONS] + c] = cand[i];
            }
        }
        __syncthreads();
        const int total = segbase[bsel - CONS] + (int)cur[bsel - CONS];
        for (int q = total + tid; q < SORTN; q += 1024) pairs[q] = 0ull;
        if (tid < 64 && (int)cur[tid] > 128) sh_big = 1;
        __syncthreads();
    } else {
        const float4* src = score4 + (size_t)b * F4PB;
        for (int n = tid; n < F4PB; n += 1024) {
            float4 v = src[n];
            float sv[4] = {v.x, v.y, v.z, v.w};
#pragma unroll
            for (int c = 0; c < 4; ++c) {
                int bn = bin_of(sv[c]);
                if (bn >= bsel) {
                    u64 key = make_key(sv[c], 4 * n + c, bn);
                    if (bn > bsel) {
                        int q = atomicAdd(&sh_cnt, 1);
                        if (q < SORTN) pairs[q] = key;
                    } else {
                        int t = atomicAdd(&sh_nc, 1);
                        if (t < CANDCAP) cand[t] = key;
                    }
                }
            }
        }
        __syncthreads();
        const int nc = min(sh_nc, CANDCAP);
        for (int i = tid; i < nc; i += 1024) {
            uint32_t vi = (uint32_t)(cand[i] >> 32);
            int g = 0, e = 0;
            for (int j = 0; j < nc; ++j) {
                uint32_t vj = (uint32_t)(cand[j] >> 32);
                g += (vj > vi);
                e += (vj == vi);
            }
            if (g < tprime && g + e >= tprime) sh_pivot = vi;
        }
        __syncthreads();
        const uint32_t pivot = sh_pivot;
        for (int i = tid; i < nc; i += 1024) {
            uint32_t vi = (uint32_t)(cand[i] >> 32);
            if (vi >= pivot) {
                int q = atomicAdd(&sh_cnt, 1);
                if (q < SORTN) pairs[q] = cand[i];
            }
        }
        __syncthreads();
        const int total = min(sh_cnt, SORTN);
        for (int q = total + tid; q < SORTN; q += 1024) pairs[q] = 0ull;
        if (tid == 0) sh_big = 1;
        __syncthreads();
    }

    if (!sh_big) {
        // per-wave segment sorts (zero barriers)
        for (int sgi = wv; sgi < 64; sgi += 16) {
            int n = (int)cur[sgi];
            if (n <= 0) continue;
            int base = segbase[sgi];
            if (n <= 64) {
                u64 e = (lane < n) ? pairs[base + lane] : 0ull;
#pragma unroll
                for (int k = 2; k <= 64; k <<= 1)
                    for (int j = k >> 1; j > 0; j >>= 1)
                        e = cs_keep(e, __shfl_xor(e, j, 64), lane, j, k);
                if (lane < n) pairs[base + lane] = e;
            } else {
                u64 e0 = (lane < n) ? pairs[base + lane] : 0ull;
                u64 e1 = (lane + 64 < n) ? pairs[base + lane + 64] : 0ull;
#pragma unroll
                for (int k = 2; k <= 128; k <<= 1) {
                    for (int j = k >> 1; j > 0; j >>= 1) {
                        if (j == 64) {
                            u64 a = e0, c = e1;
                            e0 = cs_keep(a, c, lane, 64, k);
                            e1 = cs_keep(c, a, lane + 64, 64, k);
                        } else {
                            e0 = cs_keep(e0, __shfl_xor(e0, j, 64), lane, j, k);
                            e1 = cs_keep(e1, __shfl_xor(e1, j, 64), lane + 64, j, k);
                        }
                    }
                }
                if (lane < n) pairs[base + lane] = e0;
                if (lane + 64 < n) pairs[base + lane + 64] = e1;
            }
        }
        __syncthreads();
        g_sorted[(size_t)b * SORTN + tid]        = pairs[tid];
        g_sorted[(size_t)b * SORTN + tid + 1024] = pairs[tid + 1024];
    } else {
        const int i0 = wv * 128 + lane;
        const int i1 = i0 + 64;
        u64 e0 = pairs[i0];
        u64 e1 = pairs[i1];
        for (int k = 2; k <= SORTN; k <<= 1) {
            for (int j = k >> 1; j > 0; j >>= 1) {
                if (j >= 128) {
                    pairs[i0] = e0;
                    pairs[i1] = e1;
                    __syncthreads();
                    u64 p0 = pairs[i0 ^ j];
                    u64 p1 = pairs[i1 ^ j];
                    __syncthreads();
                    e0 = cs_keep(e0, p0, i0, j, k);
                    e1 = cs_keep(e1, p1, i1, j, k);
                } else if (j == 64) {
                    u64 a = e0, c = e1;
                    e0 = cs_keep(a, c, i0, 64, k);
                    e1 = cs_keep(c, a, i1, 64, k);
                } else {
                    e0 = cs_keep(e0, __shfl_xor(e0, j, 64), i0, j, k);
                    e1 = cs_keep(e1, __shfl_xor(e1, j, 64), i1, j, k);
                }
            }
        }
        g_sorted[(size_t)b * SORTN + i0] = e0;
        g_sorted[(size_t)b * SORTN + i1] = e1;
    }
}

// ---------------- K3: decode sorted top-2000 -------------------------------
__global__ __launch_bounds__(256) void k3_decode(
    const float4* __restrict__ deltas,
    const float4* __restrict__ anchors,
    const u64*  __restrict__ g_sorted,
    float4* __restrict__ g_boxes,
    float*  __restrict__ g_area,
    int N)
{
    const int b   = blockIdx.x >> 2;
    const int s   = blockIdx.x & 3;
    const int tid = threadIdx.x;
    const int r0 = s * 512, r1 = min(r0 + 512, PRE);

    const float4* dl = deltas + (size_t)b * N;
    for (int r = r0 + tid; r < r1; r += 256) {
        u64 key = g_sorted[(size_t)b * SORTN + r];
        uint32_t idx = 0xFFFFFu - (uint32_t)(key & 0xFFFFFull);
        float4 bx = make_float4(0.f, 0.f, 0.f, 0.f);
        float  ar = 0.f;
        if (idx < (uint32_t)N) {
            float4 d  = dl[idx];
            float4 an = anchors[idx];
            float ah  = an.z - an.x;
            float aw  = an.w - an.y;
            float acy = an.x + 0.5f * ah;
            float acx = an.y + 0.5f * aw;
            float h   = expf(d.z) * ah;
            float w   = expf(d.w) * aw;
            float cy  = d.x * ah + acy;
            float cx  = d.y * aw + acx;
            float y1  = cy - 0.5f * h;
            float x1  = cx - 0.5f * w;
            bx = make_float4(y1, x1, y1 + h, x1 + w);
            ar = fmaxf(bx.z - bx.x, 0.f) * fmaxf(bx.w - bx.y, 0.f);
        }
        g_boxes[(size_t)b * PRE + r] = bx;
        g_area [(size_t)b * PRE + r] = ar;
    }
}

// ---------------- K4: suppression matrix (high-occupancy) ------------------
__global__ __launch_bounds__(256) void k4_supmat(
    const float4* __restrict__ g_boxes,
    uint32_t* __restrict__ g_supmat,     // [B*512*16] row-major
    uint32_t* __restrict__ g_supT)       // [B*512*2]  diag col-words
{
    const int b   = blockIdx.x >> 4;
    const int s   = blockIdx.x & 15;
    const int tid = threadIdx.x;

    __shared__ float4 box[TILE];
    for (int i = tid; i < TILE; i += 256)
        box[i] = g_boxes[(size_t)b * PRE + i];
    __syncthreads();

    // 32 rows x 16 words per block; row varies per lane (32x2 per wave),
    // w near-uniform (2 values/wave -> 2-addr LDS broadcast, free).
    const int rbase = s * 32;
#pragma unroll
    for (int k = 0; k < 2; ++k) {
        int idx = tid + k * 256;
        int row = rbase + (idx & 31);
        int w   = idx >> 5;
        int jbase = w << 5;
        float4 bi = box[row];
        float  ai = area_of(bi);
        uint32_t bits = 0u;
        if (jbase + 31 > row) {
#pragma unroll
            for (int c = 0; c < 32; ++c) {
                int j = jbase + c;
                float4 bj = box[j];
                float  aj = area_of(bj);
                bool gt = (j > row) & iou_gt(bi, ai, bj, aj);  // branchless
                bits |= ((uint32_t)gt) << c;
            }
        }
        g_supmat[((size_t)b * TILE + row) * 16 + w] = bits;
    }

    // transposed diagonal blocks: blocks s<8 emit chunk q=s (64 cols x 2)
    if (s < 8 && tid < 128) {
        int q  = s;
        int j  = tid >> 1;
        int w2 = tid & 1;
        int C  = q * 64 + j;
        float4 bc = box[C];
        float  ac = area_of(bc);
        uint32_t bits = 0u;
#pragma unroll
        for (int c = 0; c < 32; ++c) {
            int R = q * 64 + w2 * 32 + c;
            float4 br = box[R];
            float  ar = area_of(br);
            bool gt = (R < C) & iou_gt(br, ar, bc, ac);
            bits |= ((uint32_t)gt) << c;
        }
        g_supT[((size_t)b * TILE + C) * 2 + w2] = bits;
    }
}

// ---------------- K5: ballot-resolve chunked greedy sweep ------------------
__global__ __launch_bounds__(64) void k5_sweep(
    const uint32_t* __restrict__ g_supmat,
    const u64*    __restrict__ g_supT64,   // [B*512] diag col-words
    const float4* __restrict__ g_boxes,
    const float*  __restrict__ g_area,
    float4* __restrict__ out)
{
    const int b    = blockIdx.x;
    const int lane = threadIdx.x;

    __shared__ uint32_t kept[POST];
    __shared__ u64 sh_keepbits[TILE / 64];
    __shared__ uint32_t fmask[(PRE - TILE + 31) / 32];
    __shared__ int sh_kc;

    const u64* tdbase = g_supT64 + (size_t)b * TILE;

    uint32_t removedw = 0u;              // lanes 0..15: removed word
    int kc = 0, nq = 0;
    u64 cw_cur = tdbase[lane];
    for (int q = 0; q < TILE / 64; ++q) {
        u64 cw_next = (q < TILE / 64 - 1) ? tdbase[(q + 1) * 64 + lane] : 0ull;
        const int cbase = q << 6;
        uint32_t rlo = (uint32_t)__builtin_amdgcn_readlane((int)removedw, 2 * q);
        uint32_t rhi = (uint32_t)__builtin_amdgcn_readlane((int)removedw, 2 * q + 1);
        u64 avail = ~(((u64)rhi << 32) | rlo);
        u64 K = 0ull;
        while (avail) {                  // ballot-based greedy resolve
            int i = __ffsll((long long)avail) - 1;
            K |= (1ull << i);
            u64 supp = __ballot(((cw_cur >> i) & 1ull) != 0ull);
            avail &= ~(supp | (1ull << i));
        }
        if (lane == 0) sh_keepbits[q] = K;
        kc += __popcll(K);
        nq = q + 1;
        if (kc >= POST) break;
        if (K) {
            const int w = lane & 15;
            const int g = lane >> 4;
            const uint32_t* gs =
                g_supmat + ((size_t)b * TILE + cbase + g * 16) * 16 + w;
            uint32_t acc = 0u;
#pragma unroll
            for (int r = 0; r < 16; ++r)
                if ((K >> (g * 16 + r)) & 1ull) acc |= gs[(size_t)r * 16];
            acc |= (uint32_t)__shfl_xor((int)acc, 16, 64);
            acc |= (uint32_t)__shfl_xor((int)acc, 32, 64);
            if (lane < 16) removedw |= acc;
        }
        cw_cur = cw_next;
    }
    {
        int base = 0;
        for (int q = 0; q < nq; ++q) {
            u64 kbq = sh_keepbits[q];
            int pos = base + __popcll(kbq & ((1ull << lane) - 1));
            if (((kbq >> lane) & 1ull) && pos < POST)
                kept[pos] = (uint32_t)(q * 64 + lane);
            base += __popcll(kbq);
        }
        if (lane == 0) sh_kc = min(kc, POST);
    }
    __syncthreads();
    int kcf = sh_kc;

    // fallback beyond row 512 (exact; not taken on this data)
    if (kcf < POST) {
        for (int w = lane; w < (PRE - TILE + 31) / 32; w += 64) fmask[w] = 0u;
        __syncthreads();
        for (int j = TILE + lane; j < PRE; j += 64) {
            float4 bj = g_boxes[(size_t)b * PRE + j];
            float  aj = g_area [(size_t)b * PRE + j];
            bool supd = false;
            for (int k = 0; k < kcf; ++k) {
                int i = (int)kept[k];
                float4 bi = g_boxes[(size_t)b * PRE + i];
                float  ai = g_area [(size_t)b * PRE + i];
                if (iou_gt(bi, ai, bj, aj)) { supd = true; break; }
            }
            if (supd) atomicOr(&fmask[(j - TILE) >> 5], 1u << ((j - TILE) & 31));
        }
        __syncthreads();
        int i = TILE;
        while (i < PRE && kcf < POST) {
            while (i < PRE && ((fmask[(i - TILE) >> 5] >> ((i - TILE) & 31)) & 1u)) ++i;
            if (i >= PRE) break;
            if (lane == 0) kept[kcf] = (uint32_t)i;
            ++kcf;
            if (kcf >= POST) break;
            float4 bi = g_boxes[(size_t)b * PRE + i];
            float  ai = g_area [(size_t)b * PRE + i];
            for (int j = i + 1 + lane; j < PRE; j += 64) {
                float4 bj = g_boxes[(size_t)b * PRE + j];
                float  aj = g_area [(size_t)b * PRE + j];
                if (iou_gt(bi, ai, bj, aj))
                    atomicOr(&fmask[(j - TILE) >> 5], 1u << ((j - TILE) & 31));
            }
            ++i;
            __syncthreads();
        }
    }
    __syncthreads();

    // write clipped output
    float4* ob = out + (size_t)b * POST;
    for (int r = lane; r < POST; r += 64) {
        float4 o = make_float4(0.f, 0.f, 0.f, 0.f);
        if (r < kcf) {
            float4 bx = g_boxes[(size_t)b * PRE + kept[r]];
            o.x = fminf(fmaxf(bx.x, 0.f), 1.f);
            o.y = fminf(fmaxf(bx.y, 0.f), 1.f);
            o.z = fminf(fmaxf(bx.z, 0.f), 1.f);
            o.w = fminf(fmaxf(bx.w, 0.f), 1.f);
        }
        ob[r] = o;
    }
}

extern "C" void kernel_launch(void* const* d_in, const int* in_sizes, int n_in,
                              void* d_out, int out_size, void* d_ws, size_t ws_size,
                              hipStream_t stream) {
    const float4* deltas  = (const float4*)d_in[0];
    const float*  labels  = (const float*)d_in[1];
    const float4* anchors = (const float4*)d_in[2];
    const float4* score4  = (const float4*)labels;
    float4*       outp    = (float4*)d_out;
    const int N = in_sizes[2] / 4;      // 90000
    const int B = in_sizes[1] / N;      // 64

    // workspace (16B-aligned chunks), no zero-init required anywhere:
    // boxes | pairs | sorted | supmat | supT | area | hist | scnt
    char* ws = (char*)d_ws;
    const size_t SZ_BOXES  = (size_t)B * PRE * 16;
    const size_t SZ_PAIRS  = (size_t)B * SL * KBUF * 8;
    const size_t SZ_SORTED = (size_t)B * SORTN * 8;
    const size_t SZ_SUPMAT = (size_t)B * TILE * 16 * 4;
    const size_t SZ_SUPT   = (size_t)B * TILE * 8;
    const size_t SZ_AREA   = (size_t)B * PRE * 4;
    const size_t SZ_HIST   = (size_t)B * SL * NBINS * 4;
    float4*   g_boxes  = (float4*)ws;
    u64*      g_pairs  = (u64*)(ws + SZ_BOXES);
    u64*      g_sorted = (u64*)(ws + SZ_BOXES + SZ_PAIRS);
    uint32_t* g_supmat = (uint32_t*)(ws + SZ_BOXES + SZ_PAIRS + SZ_SORTED);
    uint32_t* g_supT   = (uint32_t*)(ws + SZ_BOXES + SZ_PAIRS + SZ_SORTED + SZ_SUPMAT);
    float*    g_area   = (float*)(ws + SZ_BOXES + SZ_PAIRS + SZ_SORTED + SZ_SUPMAT + SZ_SUPT);
    uint32_t* g_hist   = (uint32_t*)(ws + SZ_BOXES + SZ_PAIRS + SZ_SORTED + SZ_SUPMAT + SZ_SUPT + SZ_AREA);
    int*      g_scnt   = (int*)((char*)g_hist + SZ_HIST);

    k1_hist_gather<<<B * SL, 256, 0, stream>>>(score4, g_hist, g_pairs,
                                               g_scnt, N);
    k2_sort<<<B, 1024, 0, stream>>>(score4, g_pairs, g_scnt, g_hist,
                                    g_sorted, N);
    k3_decode<<<B * 4, 256, 0, stream>>>(deltas, anchors, g_sorted,
                                         g_boxes, g_area, N);
    k4_supmat<<<B * 16, 256, 0, stream>>>(g_boxes, g_supmat, g_supT);
    k5_sweep<<<B, 64, 0, stream>>>(g_supmat, (const u64*)g_supT,
                                   g_boxes, g_area, outp);
}

// Round 11
// 88.400 us; speedup vs baseline: 1.5334x; 1.0527x over previous
//
#include <hip/hip_runtime.h>
#include <stdint.h>

// RPN RoI proposal, 4-kernel pipeline, no pre-zeroed state:
//  Insight: the speculative superset {keys with bin >= CONS} contains the
//  exact top-2000 whenever |superset| >= 2000 (any non-member scores below
//  every member). So no global 2048-bin histogram is needed on the common
//  path -- sort the ~2812-key superset, take the first 2000.
//  K1 (B*16 x 256): pure threshold gather: keys with bin>=CONS into private
//     per-slice segments + raw counts. key = flip(f32)<<32 | bin<<20 |
//     (0xFFFFF-idx): u64 desc order == lax.top_k order (incl. tie-break).
//  K2 (B x 1024): 64-bin hist FROM THE KEYS (pass1, wave w = slice w);
//     1-wave suffix scan -> segment bases; counting-scatter (pass2);
//     zero-barrier per-wave segment bitonic sorts; fused DECODE of top-2000
//     (-> g_boxes/g_area, first 512 stashed in LDS); fused supT (diagonal
//     64x64 transposed col-words). Exact hist-based fallback in-branch
//     (total<2000 / total>4096 / slice>KBUF / segment>128; never taken).
//  K4 (B*16 x 256): suppression matrix rows -> g_supmat[512][16]
//     (4 blocks/CU for latency hiding, branchless inner loop).
//  K5 (B x 64): chunked greedy sweep: ffs+ballot resolve on per-lane diag
//     col-words; propagation via 64-lane parallel global reads + 2
//     shfl_xor. Early-exit at 300 kept; exact barrier-loop fallback beyond
//     row 512 (never taken); write clipped [300,4] zero-padded.

#define PRE 2000
#define POST 300
#define TILE 512
#define IOU_THR 0.7f
#define EPSV 1e-8f
#define SORTN 2048
#define NBINS 2048
#define DESTCAP 4096
#define CANDCAP 512
#define CONS 1984
#define SL 16
#define KBUF 768

typedef unsigned long long u64;

__device__ __forceinline__ uint32_t flip_f32(uint32_t b) {
    return b ^ ((uint32_t)((int32_t)b >> 31) | 0x80000000u);
}

__device__ __forceinline__ int bin_of(float s) {
    int bn = (int)(s * 2048.0f);
    return min(max(bn, 0), NBINS - 1);
}

__device__ __forceinline__ u64 make_key(float s, int idx, int bn) {
    uint32_t ub = flip_f32(__float_as_uint(s));
    return ((u64)ub << 32) | ((uint32_t)bn << 20) |
           (uint32_t)(0xFFFFF - idx);
}

__device__ __forceinline__ bool iou_gt(const float4& bi, float ai,
                                       const float4& bj, float aj) {
    float yy1 = fmaxf(bi.x, bj.x);
    float xx1 = fmaxf(bi.y, bj.y);
    float yy2 = fminf(bi.z, bj.z);
    float xx2 = fminf(bi.w, bj.w);
    float inter = fmaxf(yy2 - yy1, 0.f) * fmaxf(xx2 - xx1, 0.f);
    float iou = inter / (ai + aj - inter + EPSV);
    return iou > IOU_THR;
}

__device__ __forceinline__ float area_of(const float4& bx) {
    // identical expression to the g_area computation -> bit-exact
    return fmaxf(bx.z - bx.x, 0.f) * fmaxf(bx.w - bx.y, 0.f);
}

__device__ __forceinline__ u64 cs_keep(u64 v, u64 pv, int i, int j, int k) {
    bool lower   = ((i & j) == 0);
    bool desc    = ((i & k) == 0);
    bool keepmax = (desc == lower);
    u64 mx = v > pv ? v : pv;
    u64 mn = v > pv ? pv : v;
    return keepmax ? mx : mn;
}

// ---------------- K1: pure threshold gather --------------------------------
__global__ __launch_bounds__(256) void k1_gather(
    const float4* __restrict__ score4,
    u64* __restrict__ g_pairs,           // [B*SL*KBUF]
    int* __restrict__ g_scnt,            // [B*SL] raw counts (plain stores)
    int N)
{
    const int blk = blockIdx.x;
    const int b   = blk / SL;
    const int s   = blk % SL;
    const int tid = threadIdx.x;
    const int F4PB = N >> 2;
    const int F4PS = (F4PB + SL - 1) / SL;

    __shared__ u64 keybuf[KBUF];
    __shared__ int kcnt;

    if (tid == 0) kcnt = 0;
    __syncthreads();

    const float4* src = score4 + (size_t)b * F4PB;
    const int n0 = s * F4PS, n1 = min(n0 + F4PS, F4PB);
    for (int n = n0 + tid; n < n1; n += 256) {
        float4 v = src[n];
        float sv[4] = {v.x, v.y, v.z, v.w};
#pragma unroll
        for (int c = 0; c < 4; ++c) {
            int bn = bin_of(sv[c]);
            if (bn >= CONS) {
                int q = atomicAdd(&kcnt, 1);
                if (q < KBUF) keybuf[q] = make_key(sv[c], 4 * n + c, bn);
            }
        }
    }
    __syncthreads();

    if (tid == 0) g_scnt[b * SL + s] = kcnt;   // raw (may exceed KBUF)
    int lc = min(kcnt, KBUF);
    u64* gp = g_pairs + ((size_t)b * SL + s) * KBUF;
    for (int i = tid; i < lc; i += 256) gp[i] = keybuf[i];
}

// ---------------- K2: superset sort + decode + supT ------------------------
__global__ __launch_bounds__(1024) void k2_sort(
    const float4* __restrict__ score4,
    const u64*  __restrict__ g_pairs,
    const int*  __restrict__ g_scnt,
    const float4* __restrict__ deltas,
    const float4* __restrict__ anchors,
    float4* __restrict__ g_boxes,
    float*  __restrict__ g_area,
    uint32_t* __restrict__ g_supT,       // [B*512*2] diag col-words
    int N)
{
    const int b    = blockIdx.x;
    const int tid  = threadIdx.x;
    const int lane = tid & 63;
    const int wv   = tid >> 6;

    __shared__ u64 dest[DESTCAP];        // scatter dest / fallback key array
    __shared__ float4 sbox[TILE];        // first-512 boxes; fallback hist2048
    __shared__ u64 cand[CANDCAP];        // fallback pivot candidates
    __shared__ uint32_t hist64[64];
    __shared__ int segbase64[64];
    __shared__ uint32_t cur64[64];
    __shared__ int scnt_s[SL];
    __shared__ uint32_t wtot[16];
    __shared__ int sh_flag, sh_total, sh_bsel, sh_tprime, sh_cnt, sh_nc;
    __shared__ uint32_t sh_pivot;

    const int F4PB = N >> 2;

    if (tid < SL) scnt_s[tid] = g_scnt[b * SL + tid];
    if (tid < 64) { hist64[tid] = 0u; cur64[tid] = 0u; }
    if (tid == 0) { sh_flag = 0; sh_cnt = 0; sh_nc = 0; }
    __syncthreads();

    // ---- pass 1: 64-bin hist from keys (wave wv handles slice wv) ----
    {
        int raw = scnt_s[wv];
        if (raw > KBUF) sh_flag = 1;     // benign same-value race
        int cs = min(raw, KBUF);
        const u64* gp = g_pairs + ((size_t)b * SL + wv) * KBUF;
        for (int i = lane; i < cs; i += 64) {
            int b64 = (int)((gp[i] >> 20) & 0xFFFu) - CONS;  // in [0,64)
            atomicAdd(&hist64[b64], 1u);
        }
    }
    __syncthreads();

    // ---- 1-wave suffix scan of 64 bins ----
    if (wv == 0) {
        int h = (int)hist64[lane];
        int ssum = h;
#pragma unroll
        for (int off = 1; off < 64; off <<= 1) {
            int t = __shfl_down(ssum, off, 64);
            if (lane + off < 64) ssum += t;
        }
        segbase64[lane] = ssum - h;      // #keys in bins > lane
        if (lane == 0) sh_total = ssum;
        if (h > 128) sh_flag = 1;        // per-wave 2-reg sort cap
    }
    __syncthreads();
    const int total = sh_total;
    if (tid == 0 && (total < PRE || total > DESTCAP)) sh_flag = 1;
    __syncthreads();
    const bool flag = (sh_flag != 0);

    if (!flag) {
        // ---- pass 2: counting-scatter to bin segments ----
        int cs = min(scnt_s[wv], KBUF);
        const u64* gp = g_pairs + ((size_t)b * SL + wv) * KBUF;
        for (int i = lane; i < cs; i += 64) {
            u64 key = gp[i];
            int b64 = (int)((key >> 20) & 0xFFFu) - CONS;
            int c = (int)atomicAdd(&cur64[b64], 1u);
            dest[segbase64[b64] + c] = key;
        }
        __syncthreads();
        // ---- per-wave segment sorts (zero barriers) ----
        for (int sgi = wv; sgi < 64; sgi += 16) {
            int n = (int)cur64[sgi];
            if (n <= 0) continue;
            int base = segbase64[sgi];
            if (n <= 64) {
                u64 e = (lane < n) ? dest[base + lane] : 0ull;
#pragma unroll
                for (int k = 2; k <= 64; k <<= 1)
                    for (int j = k >> 1; j > 0; j >>= 1)
                        e = cs_keep(e, __shfl_xor(e, j, 64), lane, j, k);
                if (lane < n) dest[base + lane] = e;
            } else {                     // 65..128
                u64 e0 = (lane < n) ? dest[base + lane] : 0ull;
                u64 e1 = (lane + 64 < n) ? dest[base + lane + 64] : 0ull;
#pragma unroll
                for (int k = 2; k <= 128; k <<= 1) {
                    for (int j = k >> 1; j > 0; j >>= 1) {
                        if (j == 64) {
                            u64 a = e0, c = e1;
                            e0 = cs_keep(a, c, lane, 64, k);
                            e1 = cs_keep(c, a, lane + 64, 64, k);
                        } else {
                            e0 = cs_keep(e0, __shfl_xor(e0, j, 64), lane, j, k);
                            e1 = cs_keep(e1, __shfl_xor(e1, j, 64), lane + 64, j, k);
                        }
                    }
                }
                if (lane < n) dest[base + lane] = e0;
                if (lane + 64 < n) dest[base + lane + 64] = e1;
            }
        }
        __syncthreads();
    } else {
        // ---- exact fallback: hist-based top-2000 (never taken here) ----
        uint32_t* hist = (uint32_t*)sbox;        // 2048 bins = 8 KB alias
        hist[tid] = 0u; hist[tid + 1024] = 0u;
        if (tid == 0) { sh_cnt = 0; sh_nc = 0; }
        __syncthreads();
        const float4* src = score4 + (size_t)b * F4PB;
        for (int n = tid; n < F4PB; n += 1024) {
            float4 v = src[n];
            atomicAdd(&hist[bin_of(v.x)], 1u);
            atomicAdd(&hist[bin_of(v.y)], 1u);
            atomicAdd(&hist[bin_of(v.z)], 1u);
            atomicAdd(&hist[bin_of(v.w)], 1u);
        }
        __syncthreads();
        {   // 16-wave suffix scan
            const int i0 = wv * 128 + lane;
            const int i1 = i0 + 64;
            int h0 = (int)hist[i0];
            int h1 = (int)hist[i1];
            int s0 = h0, s1 = h1;
#pragma unroll
            for (int off = 1; off < 64; off <<= 1) {
                int t0 = __shfl_down(s0, off, 64);
                int t1 = __shfl_down(s1, off, 64);
                if (lane + off < 64) { s0 += t0; s1 += t1; }
            }
            int sum_h1 = __shfl(s1, 0, 64);
            if (lane == 0) wtot[wv] = (uint32_t)(__shfl(s0, 0, 64) + sum_h1);
            __syncthreads();
            int offtot = 0;
            for (int w2 = wv + 1; w2 < 16; ++w2) offtot += (int)wtot[w2];
            int S0 = s0 + sum_h1 + offtot;
            int S1 = s1 + offtot;
            if (S0 >= PRE && S0 - h0 < PRE) { sh_bsel = i0; sh_tprime = PRE - (S0 - h0); }
            if (S1 >= PRE && S1 - h1 < PRE) { sh_bsel = i1; sh_tprime = PRE - (S1 - h1); }
        }
        __syncthreads();
        const int bsel   = sh_bsel;
        const int tprime = sh_tprime;
        __syncthreads();       // hist consumed; sbox free for later decode
        for (int n = tid; n < F4PB; n += 1024) {
            float4 v = src[n];
            float sv[4] = {v.x, v.y, v.z, v.w};
#pragma unroll
            for (int c = 0; c < 4; ++c) {
                int bn = bin_of(sv[c]);
                if (bn >= bsel) {
                    u64 key = make_key(sv[c], 4 * n + c, bn);
                    if (bn > bsel) {
                        int q = atomicAdd(&sh_cnt, 1);
                        if (q < SORTN) dest[q] = key;
                    } else {
                        int t = atomicAdd(&sh_nc, 1);
                        if (t < CANDCAP) cand[t] = key;
                    }
                }
            }
        }
        __syncthreads();
        const int nc = min(sh_nc, CANDCAP);
        for (int i = tid; i < nc; i += 1024) {
            uint32_t vi = (uint32_t)(cand[i] >> 32);
            int g = 0, e = 0;
            for (int j = 0; j < nc; ++j) {
                uint32_t vj = (uint32_t)(cand[j] >> 32);
                g += (vj > vi);
                e += (vj == vi);
            }
            if (g < tprime && g + e >= tprime) sh_pivot = vi;
        }
        __syncthreads();
        const uint32_t pivot = sh_pivot;
        for (int i = tid; i < nc; i += 1024) {
            uint32_t vi = (uint32_t)(cand[i] >> 32);
            if (vi >= pivot) {
                int q = atomicAdd(&sh_cnt, 1);
                if (q < SORTN) dest[q] = cand[i];
            }
        }
        __syncthreads();
        const int tt = min(sh_cnt, SORTN);
        for (int q = tt + tid; q < SORTN; q += 1024) dest[q] = 0ull;
        __syncthreads();
        {   // full register bitonic over dest[0..2048)
            const int i0 = wv * 128 + lane;
            const int i1 = i0 + 64;
            u64 e0 = dest[i0];
            u64 e1 = dest[i1];
            for (int k = 2; k <= SORTN; k <<= 1) {
                for (int j = k >> 1; j > 0; j >>= 1) {
                    if (j >= 128) {
                        dest[i0] = e0;
                        dest[i1] = e1;
                        __syncthreads();
                        u64 p0 = dest[i0 ^ j];
                        u64 p1 = dest[i1 ^ j];
                        __syncthreads();
                        e0 = cs_keep(e0, p0, i0, j, k);
                        e1 = cs_keep(e1, p1, i1, j, k);
                    } else if (j == 64) {
                        u64 a = e0, c = e1;
                        e0 = cs_keep(a, c, i0, 64, k);
                        e1 = cs_keep(c, a, i1, 64, k);
                    } else {
                        e0 = cs_keep(e0, __shfl_xor(e0, j, 64), i0, j, k);
                        e1 = cs_keep(e1, __shfl_xor(e1, j, 64), i1, j, k);
                    }
                }
            }
            dest[i0] = e0;
            dest[i1] = e1;
        }
        __syncthreads();
    }

    // ---- fused decode of top-2000 (stash first 512 boxes in LDS) ----
    const float4* dl = deltas + (size_t)b * N;
    for (int r = tid; r < PRE; r += 1024) {
        u64 key = dest[r];
        uint32_t idx = 0xFFFFFu - (uint32_t)(key & 0xFFFFFull);
        float4 bx = make_float4(0.f, 0.f, 0.f, 0.f);
        float  ar = 0.f;
        if (idx < (uint32_t)N) {
            float4 d  = dl[idx];
            float4 an = anchors[idx];
            float ah  = an.z - an.x;
            float aw  = an.w - an.y;
            float acy = an.x + 0.5f * ah;
            float acx = an.y + 0.5f * aw;
            float h   = expf(d.z) * ah;
            float w   = expf(d.w) * aw;
            float cy  = d.x * ah + acy;
            float cx  = d.y * aw + acx;
            float y1  = cy - 0.5f * h;
            float x1  = cx - 0.5f * w;
            bx = make_float4(y1, x1, y1 + h, x1 + w);
            ar = fmaxf(bx.z - bx.x, 0.f) * fmaxf(bx.w - bx.y, 0.f);
        }
        g_boxes[(size_t)b * PRE + r] = bx;
        g_area [(size_t)b * PRE + r] = ar;
        if (r < TILE) sbox[r] = bx;
    }
    __syncthreads();

    // ---- fused supT: 8 chunks x 64 cols x 2 words = 1024 tasks ----
    {
        int q  = tid >> 7;
        int j  = (tid >> 1) & 63;
        int w2 = tid & 1;
        int C  = q * 64 + j;
        float4 bc = sbox[C];
        float  ac = area_of(bc);
        uint32_t bits = 0u;
#pragma unroll
        for (int c = 0; c < 32; ++c) {
            int R = q * 64 + w2 * 32 + c;
            float4 br = sbox[R];
            float  ar = area_of(br);
            bool gt = (R < C) & iou_gt(br, ar, bc, ac);
            bits |= ((uint32_t)gt) << c;
        }
        g_supT[((size_t)b * TILE + C) * 2 + w2] = bits;
    }
}

// ---------------- K4: suppression matrix (high-occupancy) ------------------
__global__ __launch_bounds__(256) void k4_supmat(
    const float4* __restrict__ g_boxes,
    uint32_t* __restrict__ g_supmat)     // [B*512*16] row-major
{
    const int b   = blockIdx.x >> 4;
    const int s   = blockIdx.x & 15;
    const int tid = threadIdx.x;

    __shared__ float4 box[TILE];
    for (int i = tid; i < TILE; i += 256)
        box[i] = g_boxes[(size_t)b * PRE + i];
    __syncthreads();

    const int rbase = s * 32;
#pragma unroll
    for (int k = 0; k < 2; ++k) {
        int idx = tid + k * 256;
        int row = rbase + (idx & 31);
        int w   = idx >> 5;
        int jbase = w << 5;
        float4 bi = box[row];
        float  ai = area_of(bi);
        uint32_t bits = 0u;
        if (jbase + 31 > row) {
#pragma unroll
            for (int c = 0; c < 32; ++c) {
                int j = jbase + c;
                float4 bj = box[j];
                float  aj = area_of(bj);
                bool gt = (j > row) & iou_gt(bi, ai, bj, aj);  // branchless
                bits |= ((uint32_t)gt) << c;
            }
        }
        g_supmat[((size_t)b * TILE + row) * 16 + w] = bits;
    }
}

// ---------------- K5: ballot-resolve chunked greedy sweep ------------------
__global__ __launch_bounds__(64) void k5_sweep(
    const uint32_t* __restrict__ g_supmat,
    const u64*    __restrict__ g_supT64,   // [B*512] diag col-words
    const float4* __restrict__ g_boxes,
    const float*  __restrict__ g_area,
    float4* __restrict__ out)
{
    const int b    = blockIdx.x;
    const int lane = threadIdx.x;

    __shared__ uint32_t kept[POST];
    __shared__ u64 sh_keepbits[TILE / 64];
    __shared__ uint32_t fmask[(PRE - TILE + 31) / 32];
    __shared__ int sh_kc;

    const u64* tdbase = g_supT64 + (size_t)b * TILE;

    uint32_t removedw = 0u;              // lanes 0..15: removed word
    int kc = 0, nq = 0;
    u64 cw_cur = tdbase[lane];
    for (int q = 0; q < TILE / 64; ++q) {
        u64 cw_next = (q < TILE / 64 - 1) ? tdbase[(q + 1) * 64 + lane] : 0ull;
        const int cbase = q << 6;
        uint32_t rlo = (uint32_t)__builtin_amdgcn_readlane((int)removedw, 2 * q);
        uint32_t rhi = (uint32_t)__builtin_amdgcn_readlane((int)removedw, 2 * q + 1);
        u64 avail = ~(((u64)rhi << 32) | rlo);
        u64 K = 0ull;
        while (avail) {                  // ballot-based greedy resolve
            int i = __ffsll((long long)avail) - 1;
            K |= (1ull << i);
            u64 supp = __ballot(((cw_cur >> i) & 1ull) != 0ull);
            avail &= ~(supp | (1ull << i));
        }
        if (lane == 0) sh_keepbits[q] = K;
        kc += __popcll(K);
        nq = q + 1;
        if (kc >= POST) break;
        if (K) {
            const int w = lane & 15;
            const int g = lane >> 4;
            const uint32_t* gs =
                g_supmat + ((size_t)b * TILE + cbase + g * 16) * 16 + w;
            uint32_t acc = 0u;
#pragma unroll
            for (int r = 0; r < 16; ++r)
                if ((K >> (g * 16 + r)) & 1ull) acc |= gs[(size_t)r * 16];
            acc |= (uint32_t)__shfl_xor((int)acc, 16, 64);
            acc |= (uint32_t)__shfl_xor((int)acc, 32, 64);
            if (lane < 16) removedw |= acc;
        }
        cw_cur = cw_next;
    }
    {
        int base = 0;
        for (int q = 0; q < nq; ++q) {
            u64 kbq = sh_keepbits[q];
            int pos = base + __popcll(kbq & ((1ull << lane) - 1));
            if (((kbq >> lane) & 1ull) && pos < POST)
                kept[pos] = (uint32_t)(q * 64 + lane);
            base += __popcll(kbq);
        }
        if (lane == 0) sh_kc = min(kc, POST);
    }
    __syncthreads();
    int kcf = sh_kc;

    // fallback beyond row 512 (exact; not taken on this data)
    if (kcf < POST) {
        for (int w = lane; w < (PRE - TILE + 31) / 32; w += 64) fmask[w] = 0u;
        __syncthreads();
        for (int j = TILE + lane; j < PRE; j += 64) {
            float4 bj = g_boxes[(size_t)b * PRE + j];
            float  aj = g_area [(size_t)b * PRE + j];
            bool supd = false;
            for (int k = 0; k < kcf; ++k) {
                int i = (int)kept[k];
                float4 bi = g_boxes[(size_t)b * PRE + i];
                float  ai = g_area [(size_t)b * PRE + i];
                if (iou_gt(bi, ai, bj, aj)) { supd = true; break; }
            }
            if (supd) atomicOr(&fmask[(j - TILE) >> 5], 1u << ((j - TILE) & 31));
        }
        __syncthreads();
        int i = TILE;
        while (i < PRE && kcf < POST) {
            while (i < PRE && ((fmask[(i - TILE) >> 5] >> ((i - TILE) & 31)) & 1u)) ++i;
            if (i >= PRE) break;
            if (lane == 0) kept[kcf] = (uint32_t)i;
            ++kcf;
            if (kcf >= POST) break;
            float4 bi = g_boxes[(size_t)b * PRE + i];
            float  ai = g_area [(size_t)b * PRE + i];
            for (int j = i + 1 + lane; j < PRE; j += 64) {
                float4 bj = g_boxes[(size_t)b * PRE + j];
                float  aj = g_area [(size_t)b * PRE + j];
                if (iou_gt(bi, ai, bj, aj))
                    atomicOr(&fmask[(j - TILE) >> 5], 1u << ((j - TILE) & 31));
            }
            ++i;
            __syncthreads();
        }
    }
    __syncthreads();

    // write clipped output
    float4* ob = out + (size_t)b * POST;
    for (int r = lane; r < POST; r += 64) {
        float4 o = make_float4(0.f, 0.f, 0.f, 0.f);
        if (r < kcf) {
            float4 bx = g_boxes[(size_t)b * PRE + kept[r]];
            o.x = fminf(fmaxf(bx.x, 0.f), 1.f);
            o.y = fminf(fmaxf(bx.y, 0.f), 1.f);
            o.z = fminf(fmaxf(bx.z, 0.f), 1.f);
            o.w = fminf(fmaxf(bx.w, 0.f), 1.f);
        }
        ob[r] = o;
    }
}

extern "C" void kernel_launch(void* const* d_in, const int* in_sizes, int n_in,
                              void* d_out, int out_size, void* d_ws, size_t ws_size,
                              hipStream_t stream) {
    const float4* deltas  = (const float4*)d_in[0];
    const float*  labels  = (const float*)d_in[1];
    const float4* anchors = (const float4*)d_in[2];
    const float4* score4  = (const float4*)labels;
    float4*       outp    = (float4*)d_out;
    const int N = in_sizes[2] / 4;      // 90000
    const int B = in_sizes[1] / N;      // 64

    // workspace (16B-aligned chunks), no zero-init required anywhere:
    // boxes | pairs | supmat | supT | area | scnt
    char* ws = (char*)d_ws;
    const size_t SZ_BOXES  = (size_t)B * PRE * 16;
    const size_t SZ_PAIRS  = (size_t)B * SL * KBUF * 8;
    const size_t SZ_SUPMAT = (size_t)B * TILE * 16 * 4;
    const size_t SZ_SUPT   = (size_t)B * TILE * 8;
    const size_t SZ_AREA   = (size_t)B * PRE * 4;
    float4*   g_boxes  = (float4*)ws;
    u64*      g_pairs  = (u64*)(ws + SZ_BOXES);
    uint32_t* g_supmat = (uint32_t*)(ws + SZ_BOXES + SZ_PAIRS);
    uint32_t* g_supT   = (uint32_t*)(ws + SZ_BOXES + SZ_PAIRS + SZ_SUPMAT);
    float*    g_area   = (float*)(ws + SZ_BOXES + SZ_PAIRS + SZ_SUPMAT + SZ_SUPT);
    int*      g_scnt   = (int*)(ws + SZ_BOXES + SZ_PAIRS + SZ_SUPMAT + SZ_SUPT + SZ_AREA);

    k1_gather<<<B * SL, 256, 0, stream>>>(score4, g_pairs, g_scnt, N);
    k2_sort<<<B, 1024, 0, stream>>>(score4, g_pairs, g_scnt, deltas, anchors,
                                    g_boxes, g_area, g_supT, N);
    k4_supmat<<<B * 16, 256, 0, stream>>>(g_boxes, g_supmat);
    k5_sweep<<<B, 64, 0, stream>>>(g_supmat, (const u64*)g_supT,
                                   g_boxes, g_area, outp);
}